// Round 1
// baseline (1516.542 us; speedup 1.0000x reference)
//
#include <hip/hip_runtime.h>
#include <math.h>

// Problem constants (match reference)
constexpr int B = 32, T = 256, D = 2048, H = 16, DK = 64;

// ---------------------------------------------------------------------------
// Kernel 1: projection GEMM (f32).  C[m,n] = sum_k A[m,k] * W[n,k]
//   A = content (B*T, D) row-major; W = k_w or v_w (H*DK, D) row-major.
//   out layout: out[((b*H + h)*T + t)*DK + dk],  m = b*T+t, n = h*DK+dk.
// 128x128 tile, BK=16, 256 threads, 8x8 micro-tile (rows split tm*4 and
// 64+tm*4 so LDS b128 reads stay at 2-way bank aliasing = free).
// ---------------------------------------------------------------------------
constexpr int BM = 128, BN = 128, BK = 16;

__global__ __launch_bounds__(256) void gemm_proj(
    const float* __restrict__ A, const float* __restrict__ W,
    float* __restrict__ out) {
  __shared__ float As[BK][BM + 4];
  __shared__ float Ws[BK][BN + 4];
  const int tid = threadIdx.x;
  const int m0 = blockIdx.x * BM;
  const int n0 = blockIdx.y * BN;
  const int tm = tid >> 4, tn = tid & 15;
  const int lrow = tid >> 1, lk = (tid & 1) * 8;
  const float* Ap = A + (size_t)(m0 + lrow) * D + lk;
  const float* Wp = W + (size_t)(n0 + lrow) * D + lk;
  float acc[8][8] = {};
  for (int k0 = 0; k0 < D; k0 += BK) {
    float4 a0 = *(const float4*)(Ap + k0);
    float4 a1 = *(const float4*)(Ap + k0 + 4);
    float4 w0 = *(const float4*)(Wp + k0);
    float4 w1 = *(const float4*)(Wp + k0 + 4);
    __syncthreads();  // previous tile fully consumed
    As[lk + 0][lrow] = a0.x; As[lk + 1][lrow] = a0.y;
    As[lk + 2][lrow] = a0.z; As[lk + 3][lrow] = a0.w;
    As[lk + 4][lrow] = a1.x; As[lk + 5][lrow] = a1.y;
    As[lk + 6][lrow] = a1.z; As[lk + 7][lrow] = a1.w;
    Ws[lk + 0][lrow] = w0.x; Ws[lk + 1][lrow] = w0.y;
    Ws[lk + 2][lrow] = w0.z; Ws[lk + 3][lrow] = w0.w;
    Ws[lk + 4][lrow] = w1.x; Ws[lk + 5][lrow] = w1.y;
    Ws[lk + 6][lrow] = w1.z; Ws[lk + 7][lrow] = w1.w;
    __syncthreads();
#pragma unroll
    for (int kk = 0; kk < BK; ++kk) {
      float a[8], w[8];
      *(float4*)&a[0] = *(const float4*)&As[kk][tm * 4];
      *(float4*)&a[4] = *(const float4*)&As[kk][64 + tm * 4];
      *(float4*)&w[0] = *(const float4*)&Ws[kk][tn * 4];
      *(float4*)&w[4] = *(const float4*)&Ws[kk][64 + tn * 4];
#pragma unroll
      for (int i = 0; i < 8; ++i)
#pragma unroll
        for (int j = 0; j < 8; ++j) acc[i][j] += a[i] * w[j];
    }
  }
  // epilogue: write to (B,H,T,DK) layout; each 64-col half is one head
  const int h0 = n0 >> 6;
#pragma unroll
  for (int ih = 0; ih < 2; ++ih) {
    const int h = h0 + ih;
    const int dk = tn * 4;
#pragma unroll
    for (int im = 0; im < 2; ++im) {
#pragma unroll
      for (int i = 0; i < 4; ++i) {
        const int m = m0 + im * 64 + tm * 4 + i;
        const int b = m >> 8, t = m & 255;
        float4 r = make_float4(acc[im * 4 + i][ih * 4 + 0],
                               acc[im * 4 + i][ih * 4 + 1],
                               acc[im * 4 + i][ih * 4 + 2],
                               acc[im * 4 + i][ih * 4 + 3]);
        *(float4*)(out + (((size_t)b * H + h) * T + t) * DK + dk) = r;
      }
    }
  }
}

// ---------------------------------------------------------------------------
// Kernel 2: beta/gamma projections.  One block per m=(b,t) row.
//   beta[b,h,t]  = sigmoid(content[b,t]·b_w[h] + b_b[h])
//   gamma[b,h,t] = sigmoid(hd[h] + content[b,t]·ts_w[h] + ts_b[h])
// ---------------------------------------------------------------------------
__global__ __launch_bounds__(256) void bg_proj(
    const float* __restrict__ content, const float* __restrict__ b_w,
    const float* __restrict__ b_b, const float* __restrict__ ts_w,
    const float* __restrict__ ts_b, const float* __restrict__ hd,
    float* __restrict__ beta_out, float* __restrict__ gamma_out) {
  __shared__ float row[D];
  const int m = blockIdx.x;
  const int b = m >> 8, t = m & 255;
  for (int i = threadIdx.x * 4; i < D; i += 1024)
    *(float4*)&row[i] = *(const float4*)(content + (size_t)m * D + i);
  __syncthreads();
  const int wave = threadIdx.x >> 6, lane = threadIdx.x & 63;
  for (int n = wave; n < 2 * H; n += 4) {
    const int h = n & (H - 1);
    const float* wr = (n < H) ? (b_w + (size_t)h * D) : (ts_w + (size_t)h * D);
    float s = 0.f;
    for (int i = lane * 4; i < D; i += 256) {
      float4 c4 = *(const float4*)&row[i];
      float4 w4 = *(const float4*)(wr + i);
      s += c4.x * w4.x + c4.y * w4.y + c4.z * w4.z + c4.w * w4.w;
    }
#pragma unroll
    for (int off = 32; off > 0; off >>= 1) s += __shfl_down(s, off, 64);
    if (lane == 0) {
      size_t o = ((size_t)b * H + h) * T + t;
      if (n < H) beta_out[o] = 1.f / (1.f + expf(-(s + b_b[h])));
      else gamma_out[o] = 1.f / (1.f + expf(-(s + ts_b[h] + hd[h])));
    }
  }
}

// ---------------------------------------------------------------------------
// Kernel 3: per-(b,h) triangular solve + rank-T update, fused epilogue.
// 512 blocks, 256 threads (thread i owns row i; rhs in 64 VGPRs).
// LDS ~150 KB -> 1 block/CU (gfx950 has 160 KB LDS/CU).
// ---------------------------------------------------------------------------
__global__ __launch_bounds__(256, 1) void solve_write(
    const float* __restrict__ kg, const float* __restrict__ vg,
    const float* __restrict__ betag, const float* __restrict__ gammag,
    const float* __restrict__ Wold, float* __restrict__ Wnew) {
  __shared__ float kT[DK][T + 1];   // [d][t], pad 257 (odd): 2-way banks max
  __shared__ float wT[DK][T + 1];   // [v][t], scaled V' for the epilogue
  __shared__ float WoT[DK * DK];    // W_old transposed: WoT[d*DK+v]=Wold[v][d]
  __shared__ float s_beta[T], s_clog[T];
  __shared__ __align__(16) float s_vpj[DK], s_kj[DK];

  const int tid = threadIdx.x;
  const int bh = blockIdx.x;
  const size_t base = (size_t)bh * T * DK;
  const float* WoG = Wold + (size_t)bh * DK * DK;

  // ---- stage k (transposed), W_old (transposed), beta/gamma ----
  for (int idx = tid * 4; idx < T * DK; idx += 1024) {
    float4 kv = *(const float4*)(kg + base + idx);
    int t = idx >> 6, d = idx & 63;
    kT[d + 0][t] = kv.x; kT[d + 1][t] = kv.y;
    kT[d + 2][t] = kv.z; kT[d + 3][t] = kv.w;
  }
  for (int idx = tid * 4; idx < DK * DK; idx += 1024) {
    float4 w4 = *(const float4*)(WoG + idx);
    int v = idx >> 6, d = idx & 63;
    WoT[(d + 0) * DK + v] = w4.x; WoT[(d + 1) * DK + v] = w4.y;
    WoT[(d + 2) * DK + v] = w4.z; WoT[(d + 3) * DK + v] = w4.w;
  }
  const float beta_i = betag[(size_t)bh * T + tid];
  const float gam = gammag[(size_t)bh * T + tid];
  const float lg = __logf(fmaxf(gam, 1e-8f));
  s_beta[tid] = beta_i;
  s_clog[tid] = lg;
  __syncthreads();
  // inclusive prefix sum of log(gamma) (serial: T=256, trivial cost)
  if (tid == 0) {
    float run = 0.f;
    for (int t = 0; t < T; ++t) { run += s_clog[t]; s_clog[t] = run; }
  }
  __syncthreads();
  const float clog_i = s_clog[tid];
  const float c_i = clog_i - lg;        // cum_log_{i-1} (0 for i=0)
  const float G_im1 = __expf(c_i);
  const float clog_T = s_clog[T - 1];

  // ---- normalize k_i, cache in regs, write back ----
  float kreg[DK];
  float nrm = 0.f;
#pragma unroll
  for (int d = 0; d < DK; ++d) { float x = kT[d][tid]; kreg[d] = x; nrm += x * x; }
  const float rn = 1.f / fmaxf(sqrtf(nrm), 1e-12f);
#pragma unroll
  for (int d = 0; d < DK; ++d) { kreg[d] *= rn; kT[d][tid] = kreg[d]; }

  // ---- rhs_i[v] = v_i[v] - G_{i-1} * sum_d Wold[v][d] k_i[d] ----
  float rhs[DK];
#pragma unroll
  for (int v = 0; v < DK; v += 4) {
    float4 vv = *(const float4*)(vg + base + (size_t)tid * DK + v);
    rhs[v] = vv.x; rhs[v + 1] = vv.y; rhs[v + 2] = vv.z; rhs[v + 3] = vv.w;
  }
#pragma unroll 1
  for (int d = 0; d < DK; ++d) {
    const float gk = G_im1 * kT[d][tid];  // own column: no barrier needed
#pragma unroll
    for (int v = 0; v < DK; ++v) rhs[v] -= gk * WoT[d * DK + v];
  }
  __syncthreads();  // normalized kT visible to all before solve

  // ---- right-looking forward substitution over j ----
  for (int j = 0; j < T - 1; ++j) {
    if (tid == j) {
#pragma unroll
      for (int v = 0; v < DK; v += 4) {
        *(float4*)&s_vpj[v] = make_float4(rhs[v], rhs[v + 1], rhs[v + 2], rhs[v + 3]);
        *(float4*)&s_kj[v] = make_float4(kreg[v], kreg[v + 1], kreg[v + 2], kreg[v + 3]);
      }
    }
    __syncthreads();
    if (tid > j) {
      float s = 0.f;
#pragma unroll
      for (int d = 0; d < DK; ++d) s += kreg[d] * s_kj[d];
      const float coef = s_beta[j] * __expf(c_i - s_clog[j]) * s;
#pragma unroll
      for (int v = 0; v < DK; ++v) rhs[v] -= coef * s_vpj[v];
    }
    __syncthreads();
  }

  // ---- epilogue: W_new = G_T*W_old + sum_t (beta_t decayT_t V'_t) k_t^T ----
  const float wcoef = beta_i * __expf(clog_T - clog_i);
#pragma unroll
  for (int v = 0; v < DK; ++v) wT[v][tid] = wcoef * rhs[v];
  __syncthreads();
  const float GT = __expf(clog_T);
  const int v0 = (tid >> 4) * 4, d0 = (tid & 15) * 4;
  float accw[4][4];
#pragma unroll
  for (int i = 0; i < 4; ++i) {
    float4 wo = *(const float4*)(WoG + (size_t)(v0 + i) * DK + d0);
    accw[i][0] = GT * wo.x; accw[i][1] = GT * wo.y;
    accw[i][2] = GT * wo.z; accw[i][3] = GT * wo.w;
  }
  for (int t = 0; t < T; ++t) {
    float wv[4], kv[4];
#pragma unroll
    for (int i = 0; i < 4; ++i) wv[i] = wT[v0 + i][t];
#pragma unroll
    for (int jj = 0; jj < 4; ++jj) kv[jj] = kT[d0 + jj][t];
#pragma unroll
    for (int i = 0; i < 4; ++i)
#pragma unroll
      for (int jj = 0; jj < 4; ++jj) accw[i][jj] += wv[i] * kv[jj];
  }
#pragma unroll
  for (int i = 0; i < 4; ++i)
    *(float4*)(Wnew + (size_t)bh * DK * DK + (size_t)(v0 + i) * DK + d0) =
        make_float4(accw[i][0], accw[i][1], accw[i][2], accw[i][3]);
}

// ---------------------------------------------------------------------------
extern "C" void kernel_launch(void* const* d_in, const int* in_sizes, int n_in,
                              void* d_out, int out_size, void* d_ws, size_t ws_size,
                              hipStream_t stream) {
  const float* W_old = (const float*)d_in[0];
  const float* content = (const float*)d_in[1];
  const float* k_w = (const float*)d_in[2];
  const float* v_w = (const float*)d_in[3];
  const float* b_w = (const float*)d_in[4];
  const float* b_b = (const float*)d_in[5];
  const float* ts_w = (const float*)d_in[6];
  const float* ts_b = (const float*)d_in[7];
  const float* hd = (const float*)d_in[8];
  float* out = (float*)d_out;

  float* ws_k = (float*)d_ws;                       // (B,H,T,DK) f32: 134 MB
  float* ws_v = ws_k + (size_t)B * H * T * DK;      // 134 MB
  float* ws_beta = ws_v + (size_t)B * H * T * DK;   // (B,H,T)
  float* ws_gamma = ws_beta + (size_t)B * H * T;

  gemm_proj<<<dim3(64, 8), 256, 0, stream>>>(content, k_w, ws_k);
  gemm_proj<<<dim3(64, 8), 256, 0, stream>>>(content, v_w, ws_v);
  bg_proj<<<dim3(B * T), 256, 0, stream>>>(content, b_w, b_b, ts_w, ts_b, hd,
                                           ws_beta, ws_gamma);
  solve_write<<<dim3(B * H), 256, 0, stream>>>(ws_k, ws_v, ws_beta, ws_gamma,
                                               W_old, out);
}

// Round 2
// 753.926 us; speedup vs baseline: 2.0115x; 2.0115x over previous
//
#include <hip/hip_runtime.h>
#include <hip/hip_bf16.h>
#include <math.h>

constexpr int B = 32, T = 256, D = 2048, H = 16, DK = 64;
constexpr size_t BHTD = (size_t)B * H * T * DK;  // 8388608

typedef __attribute__((ext_vector_type(8))) short short8;
typedef __attribute__((ext_vector_type(4))) float f32x4;

// ---------------------------------------------------------------------------
// cast f32 -> bf16, 8 elems per iteration (16B stores)
// ---------------------------------------------------------------------------
__global__ __launch_bounds__(256) void cast_bf16(
    const float* __restrict__ in, __hip_bfloat16* __restrict__ out, int n8) {
  int i = blockIdx.x * blockDim.x + threadIdx.x;
  const int stride = gridDim.x * blockDim.x;
  for (; i < n8; i += stride) {
    const float4 a = ((const float4*)in)[2 * i];
    const float4 b = ((const float4*)in)[2 * i + 1];
    __hip_bfloat16 tmp[8];
    tmp[0] = __float2bfloat16(a.x); tmp[1] = __float2bfloat16(a.y);
    tmp[2] = __float2bfloat16(a.z); tmp[3] = __float2bfloat16(a.w);
    tmp[4] = __float2bfloat16(b.x); tmp[5] = __float2bfloat16(b.y);
    tmp[6] = __float2bfloat16(b.z); tmp[7] = __float2bfloat16(b.w);
    uint4 v = *(const uint4*)tmp;
    *(uint4*)(out + 8 * (size_t)i) = v;
  }
}

// ---------------------------------------------------------------------------
// bf16 MFMA GEMM: C[m,n] = sum_k A[m,k]*Wc[n,k], M=8192, N=2048, K=2048.
// n<1024 -> k-proj dest, n>=1024 -> v-proj dest; out layout (B,H,T,DK) f32.
// 128x128 tile, BK=32, 256 thr, global_load_lds width 16, 16x16x32 MFMA.
// ---------------------------------------------------------------------------
__global__ __launch_bounds__(256) void gemm_bf16(
    const __hip_bfloat16* __restrict__ A, const __hip_bfloat16* __restrict__ Wc,
    float* __restrict__ outk) {
  __shared__ __hip_bfloat16 As[128 * 32];
  __shared__ __hip_bfloat16 Bs[128 * 32];
  const int tid = threadIdx.x;
  const int m0 = blockIdx.x * 128, n0 = blockIdx.y * 128;
  const int w = tid >> 6, lane = tid & 63;
  const int wm = w & 1, wn = w >> 1;
  const int fr = lane & 15, fq = lane >> 4;
  const int srow = w * 16 + (lane >> 2);   // staging row (pass adds 64)
  const int skc = (lane & 3) * 8;          // staging k-col
  f32x4 acc[4][4] = {};
  for (int k0 = 0; k0 < D; k0 += 32) {
#pragma unroll
    for (int p = 0; p < 2; ++p) {
      const int row = p * 64 + srow;
      const int lo = p * 4096 + w * 1024;  // byte offset in As/Bs
      __builtin_amdgcn_global_load_lds(
          (const __attribute__((address_space(1))) void*)(A + (size_t)(m0 + row) * D + k0 + skc),
          (__attribute__((address_space(3))) void*)((char*)As + lo), 16, 0, 0);
      __builtin_amdgcn_global_load_lds(
          (const __attribute__((address_space(1))) void*)(Wc + (size_t)(n0 + row) * D + k0 + skc),
          (__attribute__((address_space(3))) void*)((char*)Bs + lo), 16, 0, 0);
    }
    __syncthreads();  // drain vmcnt: tile ready
    short8 af[4], bf[4];
#pragma unroll
    for (int i = 0; i < 4; ++i) {
      af[i] = *(const short8*)(As + (wm * 64 + i * 16 + fr) * 32 + fq * 8);
      bf[i] = *(const short8*)(Bs + (wn * 64 + i * 16 + fr) * 32 + fq * 8);
    }
#pragma unroll
    for (int i = 0; i < 4; ++i)
#pragma unroll
      for (int j = 0; j < 4; ++j)
        acc[i][j] = __builtin_amdgcn_mfma_f32_16x16x32_bf16(af[i], bf[j], acc[i][j], 0, 0, 0);
    __syncthreads();  // all reads done before next staging overwrite
  }
  // epilogue: C/D layout col=lane&15, row=(lane>>4)*4+reg
#pragma unroll
  for (int i = 0; i < 4; ++i) {
    const int mbase = m0 + wm * 64 + i * 16 + fq * 4;
#pragma unroll
    for (int j = 0; j < 4; ++j) {
      const int n = n0 + wn * 64 + j * 16 + fr;
      const int h = (n >> 6) & 15, dk = n & 63;
      float* dst = outk + (size_t)(n >> 10) * BHTD;
#pragma unroll
      for (int r = 0; r < 4; ++r) {
        const int mm = mbase + r;
        const int b = mm >> 8, t = mm & 255;
        dst[(((size_t)b * H + h) * T + t) * DK + dk] = acc[i][j][r];
      }
    }
  }
}

// ---------------------------------------------------------------------------
// beta/gamma projections: 8 rows per block (kills L2 weight re-read).
// ---------------------------------------------------------------------------
__global__ __launch_bounds__(256) void bg_proj(
    const float* __restrict__ content, const float* __restrict__ b_w,
    const float* __restrict__ b_b, const float* __restrict__ ts_w,
    const float* __restrict__ ts_b, const float* __restrict__ hd,
    float* __restrict__ beta_out, float* __restrict__ gamma_out) {
  __shared__ float rows[8 * 2048];
  const int m0 = blockIdx.x * 8;
  for (int i = threadIdx.x * 4; i < 8 * 2048; i += 1024)
    *(float4*)&rows[i] = *(const float4*)(content + (size_t)m0 * D + i);
  __syncthreads();
  const int wv = threadIdx.x >> 6, lane = threadIdx.x & 63;
  for (int task = wv; task < 256; task += 4) {
    const int r = task & 7, o = task >> 3;  // o in 0..31
    const int h = o & 15;
    const float* wr = (o < 16) ? (b_w + (size_t)h * D) : (ts_w + (size_t)h * D);
    float s = 0.f;
#pragma unroll
    for (int ii = 0; ii < 8; ++ii) {
      float4 cv = *(const float4*)&rows[r * 2048 + ii * 256 + lane * 4];
      float4 w4 = *(const float4*)(wr + ii * 256 + lane * 4);
      s += cv.x * w4.x + cv.y * w4.y + cv.z * w4.z + cv.w * w4.w;
    }
#pragma unroll
    for (int off = 32; off > 0; off >>= 1) s += __shfl_down(s, off, 64);
    if (lane == 0) {
      const int mm = m0 + r, b = mm >> 8, t = mm & 255;
      const size_t oo = ((size_t)b * H + h) * T + t;
      if (o < 16) beta_out[oo] = 1.f / (1.f + __expf(-(s + b_b[h])));
      else gamma_out[oo] = 1.f / (1.f + __expf(-(s + ts_b[h] + hd[h])));
    }
  }
}

// ---------------------------------------------------------------------------
// Chunked solve via running state M (64x64) with per-chunk rescaling.
// Separable coef (i>j): A_ij = e^{c_i} * (beta_j e^{-d_j}) * (k_i . k_j).
// M_stored(c) = e^{o_c} * (Wold^T + sum_{j<chunk} beta_j e^{-d_j} k_j vp_j^T);
// all exponents within a chunk lie in [-~16, 0] -> no overflow.
// W_new = M_stored(final)^T  (epilogue free).
// ---------------------------------------------------------------------------
__global__ __launch_bounds__(256, 1) void solve_write(
    const float* __restrict__ kg, const float* __restrict__ vg,
    const float* __restrict__ betag, const float* __restrict__ gammag,
    const float* __restrict__ Wold, float* __restrict__ Wnew) {
  __shared__ float kR[256][66];   // normalized k rows (pad 66: col reads conflict-free)
  __shared__ float M[64][66];     // running state, M[d][v]
  __shared__ float S[64][66];     // chunk K K^T
  __shared__ float vpC[64][66];   // chunk rhs / scaled vp
  __shared__ float s_beta[256], s_cl[256];

  const int tid = threadIdx.x;
  const int bh = blockIdx.x;
  const size_t base = (size_t)bh * T * DK;
  const int lane = tid & 63, wv = tid >> 6;

  // ---- stage normalized k rows + beta/log-gamma ----
  {
    float kv[64];
    float nrm = 0.f;
    const float* kp = kg + base + (size_t)tid * DK;
#pragma unroll
    for (int i = 0; i < 16; ++i) {
      float4 x = *(const float4*)(kp + i * 4);
      kv[4 * i] = x.x; kv[4 * i + 1] = x.y; kv[4 * i + 2] = x.z; kv[4 * i + 3] = x.w;
      nrm += x.x * x.x + x.y * x.y + x.z * x.z + x.w * x.w;
    }
    const float rn = 1.f / fmaxf(sqrtf(nrm), 1e-12f);
#pragma unroll
    for (int i = 0; i < 32; ++i)
      *(float2*)&kR[tid][2 * i] = make_float2(kv[2 * i] * rn, kv[2 * i + 1] * rn);
  }
  s_beta[tid] = betag[(size_t)bh * T + tid];
  s_cl[tid] = __logf(fmaxf(gammag[(size_t)bh * T + tid], 1e-8f));
  __syncthreads();
  if (tid == 0) {  // serial cumsum (T=256, trivial)
    float run = 0.f;
    for (int t = 0; t < T; ++t) { run += s_cl[t]; s_cl[t] = run; }
  }
  {  // M init = Wold^T (overlaps cumsum; nothing reads M/s_cl until barrier)
    const float* Wo = Wold + (size_t)bh * DK * DK;
    const int d = tid & 63, v0 = (tid >> 6) * 16;
#pragma unroll
    for (int u = 0; u < 16; ++u) M[d][v0 + u] = Wo[(size_t)(v0 + u) * DK + d];
  }
  __syncthreads();

  for (int c = 0; c < 4; ++c) {
    const int c0 = c * 64;
    const float oc = (c == 0) ? 0.f : s_cl[c0 - 1];
    const float on = s_cl[c0 + 63];
    // ---- P1: S = K_c K_c^T (cooperative) ----
    {
      const int r = tid >> 2, j0 = (tid & 3) * 16;
      float kown[64];
#pragma unroll
      for (int i = 0; i < 32; ++i) {
        float2 y = *(const float2*)&kR[c0 + r][2 * i];
        kown[2 * i] = y.x; kown[2 * i + 1] = y.y;
      }
#pragma unroll 4
      for (int jj = 0; jj < 16; ++jj) {
        const float* krow = kR[c0 + j0 + jj];
        float s = 0.f;
#pragma unroll
        for (int i = 0; i < 32; ++i) {
          float2 y = *(const float2*)&krow[2 * i];
          s += kown[2 * i] * y.x + kown[2 * i + 1] * y.y;
        }
        S[r][j0 + jj] = s;
      }
    }
    // ---- P2: vpC = V_chunk - e^{c'} K_c M (cooperative) ----
    {
      const int r = tid >> 2, v0 = (tid & 3) * 16;
      const int gi = c0 + r;
      const float ci = (gi == 0) ? 0.f : (s_cl[gi - 1] - oc);
      const float eci = __expf(ci);
      float a2[16];
#pragma unroll
      for (int u = 0; u < 16; ++u) a2[u] = 0.f;
#pragma unroll 8
      for (int d = 0; d < 64; ++d) {
        const float kd = kR[gi][d];
#pragma unroll
        for (int u = 0; u < 8; ++u) {
          float2 mv = *(const float2*)&M[d][v0 + 2 * u];
          a2[2 * u] += kd * mv.x;
          a2[2 * u + 1] += kd * mv.y;
        }
      }
      const float* vp = vg + base + (size_t)gi * DK + v0;
#pragma unroll
      for (int u = 0; u < 4; ++u) {
        float4 vvv = *(const float4*)(vp + u * 4);
        vpC[r][v0 + 4 * u + 0] = vvv.x - eci * a2[4 * u + 0];
        vpC[r][v0 + 4 * u + 1] = vvv.y - eci * a2[4 * u + 1];
        vpC[r][v0 + 4 * u + 2] = vvv.z - eci * a2[4 * u + 2];
        vpC[r][v0 + 4 * u + 3] = vvv.w - eci * a2[4 * u + 3];
      }
    }
    __syncthreads();
    // ---- P3: intra-chunk sequential solve (wave 0, shuffle broadcast) ----
    if (wv == 0) {
      const int gi = c0 + lane;
      const float ci = (gi == 0) ? 0.f : (s_cl[gi - 1] - oc);
      float rhs[64];
#pragma unroll
      for (int v = 0; v < 32; ++v) {
        float2 y = *(const float2*)&vpC[lane][2 * v];
        rhs[2 * v] = y.x; rhs[2 * v + 1] = y.y;
      }
      for (int j = 0; j < 63; ++j) {
        const float dj = s_cl[c0 + j] - oc;
        const float co = (lane > j) ? s_beta[c0 + j] * __expf(ci - dj) * S[lane][j] : 0.f;
#pragma unroll
        for (int v = 0; v < 64; ++v) {
          const float vpj = __shfl(rhs[v], j, 64);
          rhs[v] -= co * vpj;
        }
      }
      // write u_l = beta_l * e^{(on-oc) - d'_l} * vp_l
      const float dlp = s_cl[gi] - oc;
      const float ul = s_beta[gi] * __expf((on - oc) - dlp);
#pragma unroll
      for (int v = 0; v < 32; ++v)
        *(float2*)&vpC[lane][2 * v] = make_float2(ul * rhs[2 * v], ul * rhs[2 * v + 1]);
    }
    __syncthreads();
    // ---- P4: M = e^{on-oc} * M + K_c^T U (cooperative, own-slice RMW) ----
    {
      const float rc = __expf(on - oc);
      const int d = tid & 63, v0 = (tid >> 6) * 16;
      float macc[16];
#pragma unroll
      for (int u = 0; u < 16; ++u) macc[u] = rc * M[d][v0 + u];
#pragma unroll 4
      for (int j = 0; j < 64; ++j) {
        const float kjd = kR[c0 + j][d];
#pragma unroll
        for (int u = 0; u < 8; ++u) {
          float2 uv = *(const float2*)&vpC[j][v0 + 2 * u];
          macc[2 * u] += kjd * uv.x;
          macc[2 * u + 1] += kjd * uv.y;
        }
      }
#pragma unroll
      for (int u = 0; u < 16; ++u) M[d][v0 + u] = macc[u];
    }
    __syncthreads();
  }
  // ---- epilogue: W_new[v][d] = M[d][v] ----
  {
    const int v = tid >> 2, d0 = (tid & 3) * 16;
    float* op = Wnew + (size_t)bh * DK * DK + (size_t)v * DK + d0;
#pragma unroll
    for (int u = 0; u < 4; ++u)
      *(float4*)(op + 4 * u) = make_float4(M[d0 + 4 * u + 0][v], M[d0 + 4 * u + 1][v],
                                           M[d0 + 4 * u + 2][v], M[d0 + 4 * u + 3][v]);
  }
}

// ---------------------------------------------------------------------------
extern "C" void kernel_launch(void* const* d_in, const int* in_sizes, int n_in,
                              void* d_out, int out_size, void* d_ws, size_t ws_size,
                              hipStream_t stream) {
  const float* W_old = (const float*)d_in[0];
  const float* content = (const float*)d_in[1];
  const float* k_w = (const float*)d_in[2];
  const float* v_w = (const float*)d_in[3];
  const float* b_w = (const float*)d_in[4];
  const float* b_b = (const float*)d_in[5];
  const float* ts_w = (const float*)d_in[6];
  const float* ts_b = (const float*)d_in[7];
  const float* hd = (const float*)d_in[8];
  float* out = (float*)d_out;

  float* ws_k = (float*)d_ws;                     // (B,H,T,DK) f32
  float* ws_v = ws_k + BHTD;                      // (B,H,T,DK) f32
  float* ws_beta = ws_v + BHTD;                   // (B,H,T)
  float* ws_gamma = ws_beta + (size_t)B * H * T;  // (B,H,T)
  __hip_bfloat16* c_bf = (__hip_bfloat16*)(ws_gamma + (size_t)B * H * T);
  __hip_bfloat16* w_bf = c_bf + (size_t)B * T * D;  // [k_w ; v_w] 2048x2048

  const int nC8 = (B * T * D) / 8;     // 2097152
  const int nW8 = (H * DK * D) / 8;    // 262144
  cast_bf16<<<2048, 256, 0, stream>>>(content, c_bf, nC8);
  cast_bf16<<<512, 256, 0, stream>>>(k_w, w_bf, nW8);
  cast_bf16<<<512, 256, 0, stream>>>(v_w, w_bf + (size_t)H * DK * D, nW8);
  gemm_bf16<<<dim3(64, 16), 256, 0, stream>>>(c_bf, w_bf, ws_k);
  bg_proj<<<dim3(1024), 256, 0, stream>>>(content, b_w, b_b, ts_w, ts_b, hd,
                                          ws_beta, ws_gamma);
  solve_write<<<dim3(B * H), 256, 0, stream>>>(ws_k, ws_v, ws_beta, ws_gamma,
                                               W_old, out);
}

// Round 3
// 497.952 us; speedup vs baseline: 3.0456x; 1.5141x over previous
//
#include <hip/hip_runtime.h>
#include <hip/hip_bf16.h>
#include <math.h>

constexpr int B = 32, T = 256, D = 2048, H = 16, DK = 64;
constexpr size_t BHTD = (size_t)B * H * T * DK;  // 8388608

typedef __attribute__((ext_vector_type(8))) short short8;
typedef __attribute__((ext_vector_type(4))) float f32x4;

// ---------------------------------------------------------------------------
// cast f32 -> bf16, 8 elems per iteration (16B stores)
// ---------------------------------------------------------------------------
__global__ __launch_bounds__(256) void cast_bf16(
    const float* __restrict__ in, __hip_bfloat16* __restrict__ out, int n8) {
  int i = blockIdx.x * blockDim.x + threadIdx.x;
  const int stride = gridDim.x * blockDim.x;
  for (; i < n8; i += stride) {
    const float4 a = ((const float4*)in)[2 * i];
    const float4 b = ((const float4*)in)[2 * i + 1];
    __hip_bfloat16 tmp[8];
    tmp[0] = __float2bfloat16(a.x); tmp[1] = __float2bfloat16(a.y);
    tmp[2] = __float2bfloat16(a.z); tmp[3] = __float2bfloat16(a.w);
    tmp[4] = __float2bfloat16(b.x); tmp[5] = __float2bfloat16(b.y);
    tmp[6] = __float2bfloat16(b.z); tmp[7] = __float2bfloat16(b.w);
    uint4 v = *(const uint4*)tmp;
    *(uint4*)(out + 8 * (size_t)i) = v;
  }
}

// ---------------------------------------------------------------------------
// bf16 MFMA GEMM, m97 structure. Grid: x = n-tile (16), y = m-tile (64) so
// XCD (= bid%8) sees only 2 n-tiles -> B stays L2-resident per XCD.
// ---------------------------------------------------------------------------
__global__ __launch_bounds__(256) void gemm_bf16(
    const __hip_bfloat16* __restrict__ A, const __hip_bfloat16* __restrict__ Wc,
    float* __restrict__ outk) {
  __shared__ __hip_bfloat16 As[128 * 32];
  __shared__ __hip_bfloat16 Bs[128 * 32];
  const int tid = threadIdx.x;
  const int m0 = blockIdx.y * 128, n0 = blockIdx.x * 128;
  const int w = tid >> 6, lane = tid & 63;
  const int wm = w & 1, wn = w >> 1;
  const int fr = lane & 15, fq = lane >> 4;
  const int srow = w * 16 + (lane >> 2);
  const int skc = (lane & 3) * 8;
  f32x4 acc[4][4] = {};
  for (int k0 = 0; k0 < D; k0 += 32) {
#pragma unroll
    for (int p = 0; p < 2; ++p) {
      const int row = p * 64 + srow;
      const int lo = p * 4096 + w * 1024;
      __builtin_amdgcn_global_load_lds(
          (const __attribute__((address_space(1))) void*)(A + (size_t)(m0 + row) * D + k0 + skc),
          (__attribute__((address_space(3))) void*)((char*)As + lo), 16, 0, 0);
      __builtin_amdgcn_global_load_lds(
          (const __attribute__((address_space(1))) void*)(Wc + (size_t)(n0 + row) * D + k0 + skc),
          (__attribute__((address_space(3))) void*)((char*)Bs + lo), 16, 0, 0);
    }
    __syncthreads();
    short8 af[4], bf[4];
#pragma unroll
    for (int i = 0; i < 4; ++i) {
      af[i] = *(const short8*)(As + (wm * 64 + i * 16 + fr) * 32 + fq * 8);
      bf[i] = *(const short8*)(Bs + (wn * 64 + i * 16 + fr) * 32 + fq * 8);
    }
#pragma unroll
    for (int i = 0; i < 4; ++i)
#pragma unroll
      for (int j = 0; j < 4; ++j)
        acc[i][j] = __builtin_amdgcn_mfma_f32_16x16x32_bf16(af[i], bf[j], acc[i][j], 0, 0, 0);
    __syncthreads();
  }
#pragma unroll
  for (int i = 0; i < 4; ++i) {
    const int mbase = m0 + wm * 64 + i * 16 + fq * 4;
#pragma unroll
    for (int j = 0; j < 4; ++j) {
      const int n = n0 + wn * 64 + j * 16 + fr;
      const int h = (n >> 6) & 15, dk = n & 63;
      float* dst = outk + (size_t)(n >> 10) * BHTD;
#pragma unroll
      for (int r = 0; r < 4; ++r) {
        const int mm = mbase + r;
        const int b = mm >> 8, t = mm & 255;
        dst[(((size_t)b * H + h) * T + t) * DK + dk] = acc[i][j][r];
      }
    }
  }
}

// ---------------------------------------------------------------------------
// beta/gamma projections: 8 rows per block.
// ---------------------------------------------------------------------------
__global__ __launch_bounds__(256) void bg_proj(
    const float* __restrict__ content, const float* __restrict__ b_w,
    const float* __restrict__ b_b, const float* __restrict__ ts_w,
    const float* __restrict__ ts_b, const float* __restrict__ hd,
    float* __restrict__ beta_out, float* __restrict__ gamma_out) {
  __shared__ float rows[8 * 2048];
  const int m0 = blockIdx.x * 8;
  for (int i = threadIdx.x * 4; i < 8 * 2048; i += 1024)
    *(float4*)&rows[i] = *(const float4*)(content + (size_t)m0 * D + i);
  __syncthreads();
  const int wv = threadIdx.x >> 6, lane = threadIdx.x & 63;
  for (int task = wv; task < 256; task += 4) {
    const int r = task & 7, o = task >> 3;
    const int h = o & 15;
    const float* wr = (o < 16) ? (b_w + (size_t)h * D) : (ts_w + (size_t)h * D);
    float s = 0.f;
#pragma unroll
    for (int ii = 0; ii < 8; ++ii) {
      float4 cv = *(const float4*)&rows[r * 2048 + ii * 256 + lane * 4];
      float4 w4 = *(const float4*)(wr + ii * 256 + lane * 4);
      s += cv.x * w4.x + cv.y * w4.y + cv.z * w4.z + cv.w * w4.w;
    }
#pragma unroll
    for (int off = 32; off > 0; off >>= 1) s += __shfl_down(s, off, 64);
    if (lane == 0) {
      const int mm = m0 + r, b = mm >> 8, t = mm & 255;
      const size_t oo = ((size_t)b * H + h) * T + t;
      if (o < 16) beta_out[oo] = 1.f / (1.f + __expf(-(s + b_b[h])));
      else gamma_out[oo] = 1.f / (1.f + __expf(-(s + ts_b[h] + hd[h])));
    }
  }
}

// ---------------------------------------------------------------------------
// Chunked solve. 4x4-register-tiled f32 matmuls (all LDS reads b128),
// XOR-swizzled k storage, readlane-broadcast intra-chunk solve (4-wave
// parallel over v). Math identical to R2 (verified).
// ---------------------------------------------------------------------------
__device__ __forceinline__ int kgi(int r, int g) {  // float4 index into kS
  return r * 16 + (g & 8) + ((g ^ (r >> 2)) & 7);
}
__device__ __forceinline__ float rdlane(float x, int j) {
  return __int_as_float(__builtin_amdgcn_readlane(__float_as_int(x), j));
}

__global__ __launch_bounds__(256, 1) void solve_write(
    const float* __restrict__ kg, const float* __restrict__ vg,
    const float* __restrict__ betag, const float* __restrict__ gammag,
    const float* __restrict__ Wold, float* __restrict__ Wnew) {
  __shared__ float kS[256 * 64];     // swizzled normalized k (64 KB)
  __shared__ float Mm[64][68];       // running state M[d][v]
  __shared__ float Ss[64][68];       // chunk K K^T (symmetric)
  __shared__ float Uu[64][68];       // chunk rhs / scaled vp
  __shared__ float s_beta[256], s_cl[256];
  float4* kS4 = (float4*)kS;

  const int tid = threadIdx.x;
  const int bh = blockIdx.x;
  const size_t base = (size_t)bh * T * DK;
  const int lane = tid & 63, wv = tid >> 6;
  const int th = tid >> 4, tl = tid & 15;  // 16x16 thread grid for matmuls

  // ---- stage normalized k (swizzled) ----
  {
    float kv[64];
    float nrm = 0.f;
    const float4* kp = (const float4*)(kg + base + (size_t)tid * DK);
#pragma unroll
    for (int i = 0; i < 16; ++i) {
      float4 x = kp[i];
      kv[4 * i] = x.x; kv[4 * i + 1] = x.y; kv[4 * i + 2] = x.z; kv[4 * i + 3] = x.w;
      nrm += x.x * x.x + x.y * x.y + x.z * x.z + x.w * x.w;
    }
    const float rn = 1.f / fmaxf(sqrtf(nrm), 1e-12f);
#pragma unroll
    for (int g = 0; g < 16; ++g)
      kS4[kgi(tid, g)] = make_float4(kv[4 * g] * rn, kv[4 * g + 1] * rn,
                                     kv[4 * g + 2] * rn, kv[4 * g + 3] * rn);
  }
  s_beta[tid] = betag[(size_t)bh * T + tid];
  s_cl[tid] = __logf(fmaxf(gammag[(size_t)bh * T + tid], 1e-8f));
  __syncthreads();
  if (tid == 0) {  // serial cumsum, overlapped with M init below
    float run = 0.f;
    for (int t = 0; t < T; ++t) { run += s_cl[t]; s_cl[t] = run; }
  }
  {  // M init = Wold^T
    const float* Wo = Wold + (size_t)bh * DK * DK;
    const int d = tid & 63, v0 = (tid >> 6) * 16;
#pragma unroll
    for (int u = 0; u < 16; ++u) Mm[d][v0 + u] = Wo[(size_t)(v0 + u) * DK + d];
  }
  __syncthreads();

  for (int c = 0; c < 4; ++c) {
    const int c0 = c * 64;
    const float oc = (c == 0) ? 0.f : s_cl[c0 - 1];
    const float on = s_cl[c0 + 63];

    // ---- P1: S = K_c K_c^T, 4x4 tile per thread ----
    {
      float accS[4][4] = {};
      for (int g = 0; g < 16; ++g) {
        float av[4][4], bv[4][4];
#pragma unroll
        for (int r = 0; r < 4; ++r) *(float4*)av[r] = kS4[kgi(c0 + 4 * th + r, g)];
#pragma unroll
        for (int r = 0; r < 4; ++r) *(float4*)bv[r] = kS4[kgi(c0 + 4 * tl + r, g)];
#pragma unroll
        for (int i = 0; i < 4; ++i)
#pragma unroll
          for (int j = 0; j < 4; ++j)
#pragma unroll
            for (int d = 0; d < 4; ++d) accS[i][j] += av[i][d] * bv[j][d];
      }
#pragma unroll
      for (int r = 0; r < 4; ++r)
        *(float4*)&Ss[4 * th + r][4 * tl] =
            make_float4(accS[r][0], accS[r][1], accS[r][2], accS[r][3]);
    }
    // ---- P2: U = V_chunk - e^{ci} K_c M, 4x4 tile per thread ----
    {
      float acc2[4][4] = {};
      for (int dg = 0; dg < 16; ++dg) {
        float kv[4][4], mv[4][4];
#pragma unroll
        for (int r = 0; r < 4; ++r) *(float4*)kv[r] = kS4[kgi(c0 + 4 * th + r, dg)];
#pragma unroll
        for (int r = 0; r < 4; ++r) *(float4*)mv[r] = *(const float4*)&Mm[4 * dg + r][4 * tl];
#pragma unroll
        for (int i = 0; i < 4; ++i)
#pragma unroll
          for (int d = 0; d < 4; ++d)
#pragma unroll
            for (int u = 0; u < 4; ++u) acc2[i][u] += kv[i][d] * mv[d][u];
      }
#pragma unroll
      for (int r = 0; r < 4; ++r) {
        const int gi = c0 + 4 * th + r;
        const float ci = (gi == 0) ? 0.f : s_cl[gi - 1] - oc;
        const float eci = __expf(ci);
        float4 vv = *(const float4*)(vg + base + (size_t)gi * DK + 4 * tl);
        *(float4*)&Uu[4 * th + r][4 * tl] =
            make_float4(vv.x - eci * acc2[r][0], vv.y - eci * acc2[r][1],
                        vv.z - eci * acc2[r][2], vv.w - eci * acc2[r][3]);
      }
    }
    __syncthreads();
    // ---- P3: intra-chunk solve; wave wv owns v-range [16wv,16wv+16) ----
    {
      const int gi = c0 + lane;
      const int v0 = wv * 16;
      float rhs[16];
#pragma unroll
      for (int u = 0; u < 4; ++u)
        *(float4*)&rhs[4 * u] = *(const float4*)&Uu[lane][v0 + 4 * u];
      const float ci = (gi == 0) ? 0.f : s_cl[gi - 1] - oc;
      const float ecl = __expf(ci);
      const float wgt = s_beta[gi] * __expf(-(s_cl[gi] - oc));  // beta_l e^{-d'_l}
      for (int j = 0; j < 63; ++j) {
        const float wj = rdlane(wgt, j);
        const float sv = Ss[j][lane];  // symmetric: = S[lane][j], stride-1 read
        const float co = (lane > j) ? ecl * wj * sv : 0.f;
#pragma unroll
        for (int u = 0; u < 16; ++u) rhs[u] -= co * rdlane(rhs[u], j);
      }
      const float ul = wgt * __expf(on - oc);  // beta_l e^{(on-oc)-d'_l}
#pragma unroll
      for (int u = 0; u < 4; ++u)
        *(float4*)&Uu[lane][v0 + 4 * u] =
            make_float4(ul * rhs[4 * u], ul * rhs[4 * u + 1],
                        ul * rhs[4 * u + 2], ul * rhs[4 * u + 3]);
    }
    __syncthreads();
    // ---- P4: M = e^{on-oc} M + K_c^T U, 4x4 tile per thread ----
    {
      const float rc = __expf(on - oc);
      const int d0 = 4 * th;
      float macc[4][4];
#pragma unroll
      for (int r = 0; r < 4; ++r) {
        float4 m4 = *(const float4*)&Mm[d0 + r][4 * tl];
        macc[r][0] = rc * m4.x; macc[r][1] = rc * m4.y;
        macc[r][2] = rc * m4.z; macc[r][3] = rc * m4.w;
      }
      for (int j = 0; j < 64; ++j) {
        float kj[4], uj[4];
        *(float4*)kj = kS4[kgi(c0 + j, th)];
        *(float4*)uj = *(const float4*)&Uu[j][4 * tl];
#pragma unroll
        for (int d = 0; d < 4; ++d)
#pragma unroll
          for (int u = 0; u < 4; ++u) macc[d][u] += kj[d] * uj[u];
      }
#pragma unroll
      for (int r = 0; r < 4; ++r)
        *(float4*)&Mm[d0 + r][4 * tl] =
            make_float4(macc[r][0], macc[r][1], macc[r][2], macc[r][3]);
    }
    __syncthreads();
  }
  // ---- epilogue: W_new[v][d] = M[d][v] ----
  {
    const int v = tid >> 2, d0 = (tid & 3) * 16;
    float* op = Wnew + (size_t)bh * DK * DK + (size_t)v * DK + d0;
#pragma unroll
    for (int u = 0; u < 4; ++u)
      *(float4*)(op + 4 * u) =
          make_float4(Mm[d0 + 4 * u + 0][v], Mm[d0 + 4 * u + 1][v],
                      Mm[d0 + 4 * u + 2][v], Mm[d0 + 4 * u + 3][v]);
  }
}

// ---------------------------------------------------------------------------
extern "C" void kernel_launch(void* const* d_in, const int* in_sizes, int n_in,
                              void* d_out, int out_size, void* d_ws, size_t ws_size,
                              hipStream_t stream) {
  const float* W_old = (const float*)d_in[0];
  const float* content = (const float*)d_in[1];
  const float* k_w = (const float*)d_in[2];
  const float* v_w = (const float*)d_in[3];
  const float* b_w = (const float*)d_in[4];
  const float* b_b = (const float*)d_in[5];
  const float* ts_w = (const float*)d_in[6];
  const float* ts_b = (const float*)d_in[7];
  const float* hd = (const float*)d_in[8];
  float* out = (float*)d_out;

  float* ws_k = (float*)d_ws;
  float* ws_v = ws_k + BHTD;
  float* ws_beta = ws_v + BHTD;
  float* ws_gamma = ws_beta + (size_t)B * H * T;
  __hip_bfloat16* c_bf = (__hip_bfloat16*)(ws_gamma + (size_t)B * H * T);
  __hip_bfloat16* w_bf = c_bf + (size_t)B * T * D;

  const int nC8 = (B * T * D) / 8;
  const int nW8 = (H * DK * D) / 8;
  cast_bf16<<<2048, 256, 0, stream>>>(content, c_bf, nC8);
  cast_bf16<<<512, 256, 0, stream>>>(k_w, w_bf, nW8);
  cast_bf16<<<512, 256, 0, stream>>>(v_w, w_bf + (size_t)H * DK * D, nW8);
  gemm_bf16<<<dim3(16, 64), 256, 0, stream>>>(c_bf, w_bf, ws_k);
  bg_proj<<<dim3(1024), 256, 0, stream>>>(content, b_w, b_b, ts_w, ts_b, hd,
                                          ws_beta, ws_gamma);
  solve_write<<<dim3(B * H), 256, 0, stream>>>(ws_k, ws_v, ws_beta, ws_gamma,
                                               W_old, out);
}

// Round 4
// 447.004 us; speedup vs baseline: 3.3927x; 1.1140x over previous
//
#include <hip/hip_runtime.h>
#include <hip/hip_bf16.h>
#include <math.h>

constexpr int B = 32, T = 256, D = 2048, H = 16, DK = 64;
constexpr size_t BHTD = (size_t)B * H * T * DK;  // 8388608

typedef __attribute__((ext_vector_type(8))) short short8;
typedef __attribute__((ext_vector_type(4))) float f32x4;

// ---------------------------------------------------------------------------
// cast both weight matrices f32 -> bf16 into concatenated w_bf
// ---------------------------------------------------------------------------
__global__ __launch_bounds__(256) void cast_w(
    const float* __restrict__ a, const float* __restrict__ b,
    __hip_bfloat16* __restrict__ out, int n8each) {
  int i = blockIdx.x * blockDim.x + threadIdx.x;
  const int stride = gridDim.x * blockDim.x;
  for (; i < 2 * n8each; i += stride) {
    const float* src = (i < n8each) ? a : b;
    const int idx = (i < n8each) ? i : i - n8each;
    const float4 x = ((const float4*)src)[2 * idx];
    const float4 y = ((const float4*)src)[2 * idx + 1];
    __hip_bfloat16 tmp[8];
    tmp[0] = __float2bfloat16(x.x); tmp[1] = __float2bfloat16(x.y);
    tmp[2] = __float2bfloat16(x.z); tmp[3] = __float2bfloat16(x.w);
    tmp[4] = __float2bfloat16(y.x); tmp[5] = __float2bfloat16(y.y);
    tmp[6] = __float2bfloat16(y.z); tmp[7] = __float2bfloat16(y.w);
    *(uint4*)(out + 8 * (size_t)i) = *(const uint4*)tmp;
  }
}

// ---------------------------------------------------------------------------
// beta/gamma projections + content bf16 cast (content staged once in LDS).
// ---------------------------------------------------------------------------
__global__ __launch_bounds__(256) void bg_cast(
    const float* __restrict__ content, const float* __restrict__ b_w,
    const float* __restrict__ b_b, const float* __restrict__ ts_w,
    const float* __restrict__ ts_b, const float* __restrict__ hd,
    float* __restrict__ beta_out, float* __restrict__ gamma_out,
    __hip_bfloat16* __restrict__ c_bf) {
  __shared__ float rows[8 * 2048];
  const int m0 = blockIdx.x * 8;
  for (int i = threadIdx.x * 4; i < 8 * 2048; i += 1024)
    *(float4*)&rows[i] = *(const float4*)(content + (size_t)m0 * D + i);
  __syncthreads();
  // side-output: bf16 copy of these 8 rows
  for (int i = threadIdx.x * 8; i < 8 * 2048; i += 2048) {
    __hip_bfloat16 tmp[8];
#pragma unroll
    for (int u = 0; u < 8; ++u) tmp[u] = __float2bfloat16(rows[i + u]);
    *(uint4*)(c_bf + (size_t)m0 * D + i) = *(const uint4*)tmp;
  }
  const int wv = threadIdx.x >> 6, lane = threadIdx.x & 63;
  for (int task = wv; task < 256; task += 4) {
    const int r = task & 7, o = task >> 3;
    const int h = o & 15;
    const float* wr = (o < 16) ? (b_w + (size_t)h * D) : (ts_w + (size_t)h * D);
    float s = 0.f;
#pragma unroll
    for (int ii = 0; ii < 8; ++ii) {
      float4 cv = *(const float4*)&rows[r * 2048 + ii * 256 + lane * 4];
      float4 w4 = *(const float4*)(wr + ii * 256 + lane * 4);
      s += cv.x * w4.x + cv.y * w4.y + cv.z * w4.z + cv.w * w4.w;
    }
#pragma unroll
    for (int off = 32; off > 0; off >>= 1) s += __shfl_down(s, off, 64);
    if (lane == 0) {
      const int mm = m0 + r, b = mm >> 8, t = mm & 255;
      const size_t oo = ((size_t)b * H + h) * T + t;
      if (o < 16) beta_out[oo] = 1.f / (1.f + __expf(-(s + b_b[h])));
      else gamma_out[oo] = 1.f / (1.f + __expf(-(s + ts_b[h] + hd[h])));
    }
  }
}

// ---------------------------------------------------------------------------
// bf16 MFMA GEMM (m97 structure), XCD-friendly grid (x = 16 n-tiles).
// ---------------------------------------------------------------------------
__global__ __launch_bounds__(256) void gemm_bf16(
    const __hip_bfloat16* __restrict__ A, const __hip_bfloat16* __restrict__ Wc,
    float* __restrict__ outk) {
  __shared__ __hip_bfloat16 As[128 * 32];
  __shared__ __hip_bfloat16 Bs[128 * 32];
  const int tid = threadIdx.x;
  const int m0 = blockIdx.y * 128, n0 = blockIdx.x * 128;
  const int w = tid >> 6, lane = tid & 63;
  const int wm = w & 1, wn = w >> 1;
  const int fr = lane & 15, fq = lane >> 4;
  const int srow = w * 16 + (lane >> 2);
  const int skc = (lane & 3) * 8;
  f32x4 acc[4][4] = {};
  for (int k0 = 0; k0 < D; k0 += 32) {
#pragma unroll
    for (int p = 0; p < 2; ++p) {
      const int row = p * 64 + srow;
      const int lo = p * 4096 + w * 1024;
      __builtin_amdgcn_global_load_lds(
          (const __attribute__((address_space(1))) void*)(A + (size_t)(m0 + row) * D + k0 + skc),
          (__attribute__((address_space(3))) void*)((char*)As + lo), 16, 0, 0);
      __builtin_amdgcn_global_load_lds(
          (const __attribute__((address_space(1))) void*)(Wc + (size_t)(n0 + row) * D + k0 + skc),
          (__attribute__((address_space(3))) void*)((char*)Bs + lo), 16, 0, 0);
    }
    __syncthreads();
    short8 af[4], bf[4];
#pragma unroll
    for (int i = 0; i < 4; ++i) {
      af[i] = *(const short8*)(As + (wm * 64 + i * 16 + fr) * 32 + fq * 8);
      bf[i] = *(const short8*)(Bs + (wn * 64 + i * 16 + fr) * 32 + fq * 8);
    }
#pragma unroll
    for (int i = 0; i < 4; ++i)
#pragma unroll
      for (int j = 0; j < 4; ++j)
        acc[i][j] = __builtin_amdgcn_mfma_f32_16x16x32_bf16(af[i], bf[j], acc[i][j], 0, 0, 0);
    __syncthreads();
  }
#pragma unroll
  for (int i = 0; i < 4; ++i) {
    const int mbase = m0 + wm * 64 + i * 16 + fq * 4;
#pragma unroll
    for (int j = 0; j < 4; ++j) {
      const int n = n0 + wn * 64 + j * 16 + fr;
      const int h = (n >> 6) & 15, dk = n & 63;
      float* dst = outk + (size_t)(n >> 10) * BHTD;
#pragma unroll
      for (int r = 0; r < 4; ++r) {
        const int mm = mbase + r;
        const int b = mm >> 8, t = mm & 255;
        dst[(((size_t)b * H + h) * T + t) * DK + dk] = acc[i][j][r];
      }
    }
  }
}

// ---------------------------------------------------------------------------
// Chunked solve, v3: per-chunk K staging (LDS 69 KB -> 2 blocks/CU).
// ---------------------------------------------------------------------------
__device__ __forceinline__ int cgi(int r, int g) {  // float4 index, chunk-local
  return r * 16 + (g & 8) + ((g ^ (r >> 2)) & 7);
}
__device__ __forceinline__ float rdlane(float x, int j) {
  return __int_as_float(__builtin_amdgcn_readlane(__float_as_int(x), j));
}

__global__ __launch_bounds__(256, 2) void solve_write(
    const float* __restrict__ kg, const float* __restrict__ vg,
    const float* __restrict__ betag, const float* __restrict__ gammag,
    const float* __restrict__ Wold, float* __restrict__ Wnew) {
  __shared__ float kC[64 * 64];      // swizzled per-chunk normalized K (16 KB)
  __shared__ float Mm[64][68];       // running state M[d][v]
  __shared__ float Ss[64][68];       // chunk K K^T
  __shared__ float Uu[64][68];       // chunk rhs / scaled vp
  __shared__ float s_beta[256], s_cl[256];
  float4* kC4 = (float4*)kC;

  const int tid = threadIdx.x;
  const int bh = blockIdx.x;
  const size_t base = (size_t)bh * T * DK;
  const int lane = tid & 63, wv = tid >> 6;
  const int th = tid >> 4, tl = tid & 15;

  s_beta[tid] = betag[(size_t)bh * T + tid];
  s_cl[tid] = __logf(fmaxf(gammag[(size_t)bh * T + tid], 1e-8f));
  __syncthreads();
  if (tid == 0) {  // serial cumsum, overlapped with M init below
    float run = 0.f;
    for (int t = 0; t < T; ++t) { run += s_cl[t]; s_cl[t] = run; }
  }
  {  // M init = Wold^T
    const float* Wo = Wold + (size_t)bh * DK * DK;
    const int d = tid & 63, v0 = (tid >> 6) * 16;
#pragma unroll
    for (int u = 0; u < 16; ++u) Mm[d][v0 + u] = Wo[(size_t)(v0 + u) * DK + d];
  }
  __syncthreads();

  for (int c = 0; c < 4; ++c) {
    const int c0 = c * 64;
    const float oc = (c == 0) ? 0.f : s_cl[c0 - 1];
    const float on = s_cl[c0 + 63];

    // ---- stage chunk K, normalized; 4 lanes per row ----
    {
      const int r = tid >> 2, p = tid & 3;
      const float4* kp = (const float4*)(kg + base + (size_t)(c0 + r) * DK + p * 16);
      float4 x0 = kp[0], x1 = kp[1], x2 = kp[2], x3 = kp[3];
      float nrm = x0.x * x0.x + x0.y * x0.y + x0.z * x0.z + x0.w * x0.w +
                  x1.x * x1.x + x1.y * x1.y + x1.z * x1.z + x1.w * x1.w +
                  x2.x * x2.x + x2.y * x2.y + x2.z * x2.z + x2.w * x2.w +
                  x3.x * x3.x + x3.y * x3.y + x3.z * x3.z + x3.w * x3.w;
      nrm += __shfl_xor(nrm, 1, 64);
      nrm += __shfl_xor(nrm, 2, 64);
      const float rn = 1.f / fmaxf(sqrtf(nrm), 1e-12f);
      kC4[cgi(r, 4 * p + 0)] = make_float4(x0.x * rn, x0.y * rn, x0.z * rn, x0.w * rn);
      kC4[cgi(r, 4 * p + 1)] = make_float4(x1.x * rn, x1.y * rn, x1.z * rn, x1.w * rn);
      kC4[cgi(r, 4 * p + 2)] = make_float4(x2.x * rn, x2.y * rn, x2.z * rn, x2.w * rn);
      kC4[cgi(r, 4 * p + 3)] = make_float4(x3.x * rn, x3.y * rn, x3.z * rn, x3.w * rn);
    }
    __syncthreads();

    // ---- P1: S = K_c K_c^T, 4x4 tile per thread ----
    {
      float accS[4][4] = {};
      for (int g = 0; g < 16; ++g) {
        float av[4][4], bv[4][4];
#pragma unroll
        for (int r = 0; r < 4; ++r) *(float4*)av[r] = kC4[cgi(4 * th + r, g)];
#pragma unroll
        for (int r = 0; r < 4; ++r) *(float4*)bv[r] = kC4[cgi(4 * tl + r, g)];
#pragma unroll
        for (int i = 0; i < 4; ++i)
#pragma unroll
          for (int j = 0; j < 4; ++j)
#pragma unroll
            for (int d = 0; d < 4; ++d) accS[i][j] += av[i][d] * bv[j][d];
      }
#pragma unroll
      for (int r = 0; r < 4; ++r)
        *(float4*)&Ss[4 * th + r][4 * tl] =
            make_float4(accS[r][0], accS[r][1], accS[r][2], accS[r][3]);
    }
    // ---- P2: U = V_chunk - e^{ci} K_c M ----
    {
      float acc2[4][4] = {};
      for (int dg = 0; dg < 16; ++dg) {
        float kv[4][4], mv[4][4];
#pragma unroll
        for (int r = 0; r < 4; ++r) *(float4*)kv[r] = kC4[cgi(4 * th + r, dg)];
#pragma unroll
        for (int r = 0; r < 4; ++r) *(float4*)mv[r] = *(const float4*)&Mm[4 * dg + r][4 * tl];
#pragma unroll
        for (int i = 0; i < 4; ++i)
#pragma unroll
          for (int d = 0; d < 4; ++d)
#pragma unroll
            for (int u = 0; u < 4; ++u) acc2[i][u] += kv[i][d] * mv[d][u];
      }
#pragma unroll
      for (int r = 0; r < 4; ++r) {
        const int gi = c0 + 4 * th + r;
        const float ci = (gi == 0) ? 0.f : s_cl[gi - 1] - oc;
        const float eci = __expf(ci);
        float4 vv = *(const float4*)(vg + base + (size_t)gi * DK + 4 * tl);
        *(float4*)&Uu[4 * th + r][4 * tl] =
            make_float4(vv.x - eci * acc2[r][0], vv.y - eci * acc2[r][1],
                        vv.z - eci * acc2[r][2], vv.w - eci * acc2[r][3]);
      }
    }
    __syncthreads();
    // ---- P3: intra-chunk solve; wave wv owns v-range [16wv,16wv+16) ----
    {
      const int gi = c0 + lane;
      const int v0 = wv * 16;
      float rhs[16];
#pragma unroll
      for (int u = 0; u < 4; ++u)
        *(float4*)&rhs[4 * u] = *(const float4*)&Uu[lane][v0 + 4 * u];
      const float ci = (gi == 0) ? 0.f : s_cl[gi - 1] - oc;
      const float ecl = __expf(ci);
      const float wgt = s_beta[gi] * __expf(-(s_cl[gi] - oc));  // beta_l e^{-d'_l}
      for (int j = 0; j < 63; ++j) {
        const float wj = rdlane(wgt, j);
        const float sv = Ss[j][lane];  // symmetric, stride-1 read
        const float co = (lane > j) ? ecl * wj * sv : 0.f;
#pragma unroll
        for (int u = 0; u < 16; ++u) rhs[u] -= co * rdlane(rhs[u], j);
      }
      const float ul = wgt * __expf(on - oc);
#pragma unroll
      for (int u = 0; u < 4; ++u)
        *(float4*)&Uu[lane][v0 + 4 * u] =
            make_float4(ul * rhs[4 * u], ul * rhs[4 * u + 1],
                        ul * rhs[4 * u + 2], ul * rhs[4 * u + 3]);
    }
    __syncthreads();
    // ---- P4: M = e^{on-oc} M + K_c^T U ----
    {
      const float rc = __expf(on - oc);
      const int d0 = 4 * th;
      float macc[4][4];
#pragma unroll
      for (int r = 0; r < 4; ++r) {
        float4 m4 = *(const float4*)&Mm[d0 + r][4 * tl];
        macc[r][0] = rc * m4.x; macc[r][1] = rc * m4.y;
        macc[r][2] = rc * m4.z; macc[r][3] = rc * m4.w;
      }
      for (int j = 0; j < 64; ++j) {
        float kj[4], uj[4];
        *(float4*)kj = kC4[cgi(j, th)];
        *(float4*)uj = *(const float4*)&Uu[j][4 * tl];
#pragma unroll
        for (int d = 0; d < 4; ++d)
#pragma unroll
          for (int u = 0; u < 4; ++u) macc[d][u] += kj[d] * uj[u];
      }
#pragma unroll
      for (int r = 0; r < 4; ++r)
        *(float4*)&Mm[d0 + r][4 * tl] =
            make_float4(macc[r][0], macc[r][1], macc[r][2], macc[r][3]);
    }
    __syncthreads();
  }
  // ---- epilogue: W_new[v][d] = M[d][v] ----
  {
    const int v = tid >> 2, d0 = (tid & 3) * 16;
    float* op = Wnew + (size_t)bh * DK * DK + (size_t)v * DK + d0;
#pragma unroll
    for (int u = 0; u < 4; ++u)
      *(float4*)(op + 4 * u) =
          make_float4(Mm[d0 + 4 * u + 0][v], Mm[d0 + 4 * u + 1][v],
                      Mm[d0 + 4 * u + 2][v], Mm[d0 + 4 * u + 3][v]);
  }
}

// ---------------------------------------------------------------------------
extern "C" void kernel_launch(void* const* d_in, const int* in_sizes, int n_in,
                              void* d_out, int out_size, void* d_ws, size_t ws_size,
                              hipStream_t stream) {
  const float* W_old = (const float*)d_in[0];
  const float* content = (const float*)d_in[1];
  const float* k_w = (const float*)d_in[2];
  const float* v_w = (const float*)d_in[3];
  const float* b_w = (const float*)d_in[4];
  const float* b_b = (const float*)d_in[5];
  const float* ts_w = (const float*)d_in[6];
  const float* ts_b = (const float*)d_in[7];
  const float* hd = (const float*)d_in[8];
  float* out = (float*)d_out;

  float* ws_k = (float*)d_ws;
  float* ws_v = ws_k + BHTD;
  float* ws_beta = ws_v + BHTD;
  float* ws_gamma = ws_beta + (size_t)B * H * T;
  __hip_bfloat16* c_bf = (__hip_bfloat16*)(ws_gamma + (size_t)B * H * T);
  __hip_bfloat16* w_bf = c_bf + (size_t)B * T * D;

  const int nW8 = (H * DK * D) / 8;  // 262144
  cast_w<<<1024, 256, 0, stream>>>(k_w, v_w, w_bf, nW8);
  bg_cast<<<1024, 256, 0, stream>>>(content, b_w, b_b, ts_w, ts_b, hd,
                                    ws_beta, ws_gamma, c_bf);
  gemm_bf16<<<dim3(16, 64), 256, 0, stream>>>(c_bf, w_bf, ws_k);
  solve_write<<<dim3(B * H), 256, 0, stream>>>(ws_k, ws_v, ws_beta, ws_gamma,
                                               W_old, out);
}

// Round 5
// 379.278 us; speedup vs baseline: 3.9985x; 1.1786x over previous
//
#include <hip/hip_runtime.h>
#include <hip/hip_bf16.h>
#include <math.h>

constexpr int B = 32, T = 256, D = 2048, H = 16, DK = 64;
constexpr size_t BHTD = (size_t)B * H * T * DK;  // 8388608
constexpr int NC8 = (B * T * D) / 8;             // 2097152
constexpr int NW8 = (H * DK * D) / 8;            // 262144
constexpr int NB8 = (H * D) / 8;                 // 4096

typedef __attribute__((ext_vector_type(8))) short short8;
typedef __attribute__((ext_vector_type(4))) float f32x4;

// ---------------------------------------------------------------------------
// one grid-stride cast kernel: content -> c_bf; [k_w;v_w;b_w;ts_w] -> w_bf
// w_bf row layout: 0..1023 k_w, 1024..2047 v_w, 2048..2063 b_w, 2064..2079 ts_w
// ---------------------------------------------------------------------------
__global__ __launch_bounds__(256) void cast_all(
    const float* __restrict__ content, const float* __restrict__ k_w,
    const float* __restrict__ v_w, const float* __restrict__ b_w,
    const float* __restrict__ ts_w, __hip_bfloat16* __restrict__ c_bf,
    __hip_bfloat16* __restrict__ w_bf) {
  const int total = NC8 + 2 * NW8 + 2 * NB8;
  int i = blockIdx.x * blockDim.x + threadIdx.x;
  const int stride = gridDim.x * blockDim.x;
  for (; i < total; i += stride) {
    const float* src;
    __hip_bfloat16* dst;
    int idx;
    if (i < NC8) { src = content; dst = c_bf; idx = i; }
    else if (i < NC8 + NW8) { src = k_w; dst = w_bf; idx = i - NC8; }
    else if (i < NC8 + 2 * NW8) {
      src = v_w; dst = w_bf + (size_t)1024 * D; idx = i - NC8 - NW8;
    } else if (i < NC8 + 2 * NW8 + NB8) {
      src = b_w; dst = w_bf + (size_t)2048 * D; idx = i - NC8 - 2 * NW8;
    } else {
      src = ts_w; dst = w_bf + (size_t)2064 * D; idx = i - NC8 - 2 * NW8 - NB8;
    }
    const float4 x = ((const float4*)src)[2 * idx];
    const float4 y = ((const float4*)src)[2 * idx + 1];
    __hip_bfloat16 tmp[8];
    tmp[0] = __float2bfloat16(x.x); tmp[1] = __float2bfloat16(x.y);
    tmp[2] = __float2bfloat16(x.z); tmp[3] = __float2bfloat16(x.w);
    tmp[4] = __float2bfloat16(y.x); tmp[5] = __float2bfloat16(y.y);
    tmp[6] = __float2bfloat16(y.z); tmp[7] = __float2bfloat16(y.w);
    *(uint4*)(dst + 8 * (size_t)idx) = *(const uint4*)tmp;
  }
}

// ---------------------------------------------------------------------------
// bf16 MFMA GEMM (m97 structure). grid (17,64): n-tiles 0..15 = k/v proj,
// n-tile 16 = beta/gamma logits with fused sigmoid epilogue.
// ---------------------------------------------------------------------------
__global__ __launch_bounds__(256) void gemm_bf16(
    const __hip_bfloat16* __restrict__ A, const __hip_bfloat16* __restrict__ Wc,
    float* __restrict__ outk, const float* __restrict__ b_b,
    const float* __restrict__ ts_b, const float* __restrict__ hd,
    float* __restrict__ beta_out, float* __restrict__ gamma_out) {
  __shared__ __hip_bfloat16 As[128 * 32];
  __shared__ __hip_bfloat16 Bs[128 * 32];
  const int tid = threadIdx.x;
  const int m0 = blockIdx.y * 128, n0 = blockIdx.x * 128;
  const int w = tid >> 6, lane = tid & 63;
  const int wm = w & 1, wn = w >> 1;
  const int fr = lane & 15, fq = lane >> 4;
  const int srow = w * 16 + (lane >> 2);
  const int skc = (lane & 3) * 8;
  f32x4 acc[4][4] = {};
  for (int k0 = 0; k0 < D; k0 += 32) {
#pragma unroll
    for (int p = 0; p < 2; ++p) {
      const int row = p * 64 + srow;
      const int lo = p * 4096 + w * 1024;
      __builtin_amdgcn_global_load_lds(
          (const __attribute__((address_space(1))) void*)(A + (size_t)(m0 + row) * D + k0 + skc),
          (__attribute__((address_space(3))) void*)((char*)As + lo), 16, 0, 0);
      __builtin_amdgcn_global_load_lds(
          (const __attribute__((address_space(1))) void*)(Wc + (size_t)(n0 + row) * D + k0 + skc),
          (__attribute__((address_space(3))) void*)((char*)Bs + lo), 16, 0, 0);
    }
    __syncthreads();
    short8 af[4], bf[4];
#pragma unroll
    for (int i = 0; i < 4; ++i) {
      af[i] = *(const short8*)(As + (wm * 64 + i * 16 + fr) * 32 + fq * 8);
      bf[i] = *(const short8*)(Bs + (wn * 64 + i * 16 + fr) * 32 + fq * 8);
    }
#pragma unroll
    for (int i = 0; i < 4; ++i)
#pragma unroll
      for (int j = 0; j < 4; ++j)
        acc[i][j] = __builtin_amdgcn_mfma_f32_16x16x32_bf16(af[i], bf[j], acc[i][j], 0, 0, 0);
    __syncthreads();
  }
  if (n0 < 2048) {  // k/v projection tiles
#pragma unroll
    for (int i = 0; i < 4; ++i) {
      const int mbase = m0 + wm * 64 + i * 16 + fq * 4;
#pragma unroll
      for (int j = 0; j < 4; ++j) {
        const int n = n0 + wn * 64 + j * 16 + fr;
        const int h = (n >> 6) & 15, dk = n & 63;
        float* dst = outk + (size_t)(n >> 10) * BHTD;
#pragma unroll
        for (int r = 0; r < 4; ++r) {
          const int mm = mbase + r;
          const int b = mm >> 8, t = mm & 255;
          dst[(((size_t)b * H + h) * T + t) * DK + dk] = acc[i][j][r];
        }
      }
    }
  } else if (wn == 0) {  // beta/gamma tile: cols 0..15 beta, 16..31 gamma
    const int h = fr;
    const float bias_b = b_b[h];
    const float bias_g = ts_b[h] + hd[h];
#pragma unroll
    for (int i = 0; i < 4; ++i) {
      const int mbase = m0 + wm * 64 + i * 16 + fq * 4;
#pragma unroll
      for (int r = 0; r < 4; ++r) {
        const int mm = mbase + r;
        const int b = mm >> 8, t = mm & 255;
        const size_t oo = ((size_t)b * H + h) * T + t;
        beta_out[oo] = 1.f / (1.f + __expf(-(acc[i][0][r] + bias_b)));
        gamma_out[oo] = 1.f / (1.f + __expf(-(acc[i][1][r] + bias_g)));
      }
    }
  }
}

// ---------------------------------------------------------------------------
// Chunked solve (unchanged from R4): per-chunk K staging, 2 blocks/CU.
// ---------------------------------------------------------------------------
__device__ __forceinline__ int cgi(int r, int g) {  // float4 index, chunk-local
  return r * 16 + (g & 8) + ((g ^ (r >> 2)) & 7);
}
__device__ __forceinline__ float rdlane(float x, int j) {
  return __int_as_float(__builtin_amdgcn_readlane(__float_as_int(x), j));
}

__global__ __launch_bounds__(256, 2) void solve_write(
    const float* __restrict__ kg, const float* __restrict__ vg,
    const float* __restrict__ betag, const float* __restrict__ gammag,
    const float* __restrict__ Wold, float* __restrict__ Wnew) {
  __shared__ float kC[64 * 64];
  __shared__ float Mm[64][68];
  __shared__ float Ss[64][68];
  __shared__ float Uu[64][68];
  __shared__ float s_beta[256], s_cl[256];
  float4* kC4 = (float4*)kC;

  const int tid = threadIdx.x;
  const int bh = blockIdx.x;
  const size_t base = (size_t)bh * T * DK;
  const int lane = tid & 63, wv = tid >> 6;
  const int th = tid >> 4, tl = tid & 15;

  s_beta[tid] = betag[(size_t)bh * T + tid];
  s_cl[tid] = __logf(fmaxf(gammag[(size_t)bh * T + tid], 1e-8f));
  __syncthreads();
  if (tid == 0) {
    float run = 0.f;
    for (int t = 0; t < T; ++t) { run += s_cl[t]; s_cl[t] = run; }
  }
  {  // M init = Wold^T
    const float* Wo = Wold + (size_t)bh * DK * DK;
    const int d = tid & 63, v0 = (tid >> 6) * 16;
#pragma unroll
    for (int u = 0; u < 16; ++u) Mm[d][v0 + u] = Wo[(size_t)(v0 + u) * DK + d];
  }
  __syncthreads();

  for (int c = 0; c < 4; ++c) {
    const int c0 = c * 64;
    const float oc = (c == 0) ? 0.f : s_cl[c0 - 1];
    const float on = s_cl[c0 + 63];

    {  // stage chunk K, normalized; 4 lanes per row
      const int r = tid >> 2, p = tid & 3;
      const float4* kp = (const float4*)(kg + base + (size_t)(c0 + r) * DK + p * 16);
      float4 x0 = kp[0], x1 = kp[1], x2 = kp[2], x3 = kp[3];
      float nrm = x0.x * x0.x + x0.y * x0.y + x0.z * x0.z + x0.w * x0.w +
                  x1.x * x1.x + x1.y * x1.y + x1.z * x1.z + x1.w * x1.w +
                  x2.x * x2.x + x2.y * x2.y + x2.z * x2.z + x2.w * x2.w +
                  x3.x * x3.x + x3.y * x3.y + x3.z * x3.z + x3.w * x3.w;
      nrm += __shfl_xor(nrm, 1, 64);
      nrm += __shfl_xor(nrm, 2, 64);
      const float rn = 1.f / fmaxf(sqrtf(nrm), 1e-12f);
      kC4[cgi(r, 4 * p + 0)] = make_float4(x0.x * rn, x0.y * rn, x0.z * rn, x0.w * rn);
      kC4[cgi(r, 4 * p + 1)] = make_float4(x1.x * rn, x1.y * rn, x1.z * rn, x1.w * rn);
      kC4[cgi(r, 4 * p + 2)] = make_float4(x2.x * rn, x2.y * rn, x2.z * rn, x2.w * rn);
      kC4[cgi(r, 4 * p + 3)] = make_float4(x3.x * rn, x3.y * rn, x3.z * rn, x3.w * rn);
    }
    __syncthreads();

    {  // P1: S = K_c K_c^T
      float accS[4][4] = {};
      for (int g = 0; g < 16; ++g) {
        float av[4][4], bv[4][4];
#pragma unroll
        for (int r = 0; r < 4; ++r) *(float4*)av[r] = kC4[cgi(4 * th + r, g)];
#pragma unroll
        for (int r = 0; r < 4; ++r) *(float4*)bv[r] = kC4[cgi(4 * tl + r, g)];
#pragma unroll
        for (int i = 0; i < 4; ++i)
#pragma unroll
          for (int j = 0; j < 4; ++j)
#pragma unroll
            for (int d = 0; d < 4; ++d) accS[i][j] += av[i][d] * bv[j][d];
      }
#pragma unroll
      for (int r = 0; r < 4; ++r)
        *(float4*)&Ss[4 * th + r][4 * tl] =
            make_float4(accS[r][0], accS[r][1], accS[r][2], accS[r][3]);
    }
    {  // P2: U = V_chunk - e^{ci} K_c M
      float acc2[4][4] = {};
      for (int dg = 0; dg < 16; ++dg) {
        float kv[4][4], mv[4][4];
#pragma unroll
        for (int r = 0; r < 4; ++r) *(float4*)kv[r] = kC4[cgi(4 * th + r, dg)];
#pragma unroll
        for (int r = 0; r < 4; ++r) *(float4*)mv[r] = *(const float4*)&Mm[4 * dg + r][4 * tl];
#pragma unroll
        for (int i = 0; i < 4; ++i)
#pragma unroll
          for (int d = 0; d < 4; ++d)
#pragma unroll
            for (int u = 0; u < 4; ++u) acc2[i][u] += kv[i][d] * mv[d][u];
      }
#pragma unroll
      for (int r = 0; r < 4; ++r) {
        const int gi = c0 + 4 * th + r;
        const float ci = (gi == 0) ? 0.f : s_cl[gi - 1] - oc;
        const float eci = __expf(ci);
        float4 vv = *(const float4*)(vg + base + (size_t)gi * DK + 4 * tl);
        *(float4*)&Uu[4 * th + r][4 * tl] =
            make_float4(vv.x - eci * acc2[r][0], vv.y - eci * acc2[r][1],
                        vv.z - eci * acc2[r][2], vv.w - eci * acc2[r][3]);
      }
    }
    __syncthreads();
    {  // P3: intra-chunk solve; wave wv owns v-range [16wv,16wv+16)
      const int gi = c0 + lane;
      const int v0 = wv * 16;
      float rhs[16];
#pragma unroll
      for (int u = 0; u < 4; ++u)
        *(float4*)&rhs[4 * u] = *(const float4*)&Uu[lane][v0 + 4 * u];
      const float ci = (gi == 0) ? 0.f : s_cl[gi - 1] - oc;
      const float ecl = __expf(ci);
      const float wgt = s_beta[gi] * __expf(-(s_cl[gi] - oc));
      for (int j = 0; j < 63; ++j) {
        const float wj = rdlane(wgt, j);
        const float sv = Ss[j][lane];
        const float co = (lane > j) ? ecl * wj * sv : 0.f;
#pragma unroll
        for (int u = 0; u < 16; ++u) rhs[u] -= co * rdlane(rhs[u], j);
      }
      const float ul = wgt * __expf(on - oc);
#pragma unroll
      for (int u = 0; u < 4; ++u)
        *(float4*)&Uu[lane][v0 + 4 * u] =
            make_float4(ul * rhs[4 * u], ul * rhs[4 * u + 1],
                        ul * rhs[4 * u + 2], ul * rhs[4 * u + 3]);
    }
    __syncthreads();
    {  // P4: M = e^{on-oc} M + K_c^T U
      const float rc = __expf(on - oc);
      const int d0 = 4 * th;
      float macc[4][4];
#pragma unroll
      for (int r = 0; r < 4; ++r) {
        float4 m4 = *(const float4*)&Mm[d0 + r][4 * tl];
        macc[r][0] = rc * m4.x; macc[r][1] = rc * m4.y;
        macc[r][2] = rc * m4.z; macc[r][3] = rc * m4.w;
      }
      for (int j = 0; j < 64; ++j) {
        float kj[4], uj[4];
        *(float4*)kj = kC4[cgi(j, th)];
        *(float4*)uj = *(const float4*)&Uu[j][4 * tl];
#pragma unroll
        for (int d = 0; d < 4; ++d)
#pragma unroll
          for (int u = 0; u < 4; ++u) macc[d][u] += kj[d] * uj[u];
      }
#pragma unroll
      for (int r = 0; r < 4; ++r)
        *(float4*)&Mm[d0 + r][4 * tl] =
            make_float4(macc[r][0], macc[r][1], macc[r][2], macc[r][3]);
    }
    __syncthreads();
  }
  {  // epilogue: W_new[v][d] = M[d][v]
    const int v = tid >> 2, d0 = (tid & 3) * 16;
    float* op = Wnew + (size_t)bh * DK * DK + (size_t)v * DK + d0;
#pragma unroll
    for (int u = 0; u < 4; ++u)
      *(float4*)(op + 4 * u) =
          make_float4(Mm[d0 + 4 * u + 0][v], Mm[d0 + 4 * u + 1][v],
                      Mm[d0 + 4 * u + 2][v], Mm[d0 + 4 * u + 3][v]);
  }
}

// ---------------------------------------------------------------------------
extern "C" void kernel_launch(void* const* d_in, const int* in_sizes, int n_in,
                              void* d_out, int out_size, void* d_ws, size_t ws_size,
                              hipStream_t stream) {
  const float* W_old = (const float*)d_in[0];
  const float* content = (const float*)d_in[1];
  const float* k_w = (const float*)d_in[2];
  const float* v_w = (const float*)d_in[3];
  const float* b_w = (const float*)d_in[4];
  const float* b_b = (const float*)d_in[5];
  const float* ts_w = (const float*)d_in[6];
  const float* ts_b = (const float*)d_in[7];
  const float* hd = (const float*)d_in[8];
  float* out = (float*)d_out;

  float* ws_k = (float*)d_ws;
  float* ws_v = ws_k + BHTD;
  float* ws_beta = ws_v + BHTD;
  float* ws_gamma = ws_beta + (size_t)B * H * T;
  __hip_bfloat16* c_bf = (__hip_bfloat16*)(ws_gamma + (size_t)B * H * T);
  __hip_bfloat16* w_bf = c_bf + (size_t)B * T * D;  // 2176 x 2048 region

  cast_all<<<2048, 256, 0, stream>>>(content, k_w, v_w, b_w, ts_w, c_bf, w_bf);
  gemm_bf16<<<dim3(17, 64), 256, 0, stream>>>(c_bf, w_bf, ws_k, b_b, ts_b, hd,
                                              ws_beta, ws_gamma);
  solve_write<<<dim3(B * H), 256, 0, stream>>>(ws_k, ws_v, ws_beta, ws_gamma,
                                               W_old, out);
}

// Round 6
// 376.020 us; speedup vs baseline: 4.0331x; 1.0087x over previous
//
#include <hip/hip_runtime.h>
#include <hip/hip_bf16.h>
#include <math.h>

constexpr int B = 32, T = 256, D = 2048, H = 16, DK = 64;
constexpr size_t BHTD = (size_t)B * H * T * DK;  // 8388608
constexpr int NC8 = (B * T * D) / 8;             // 2097152
constexpr int NW8 = (H * DK * D) / 8;            // 262144
constexpr int NB8 = (H * D) / 8;                 // 4096

typedef __attribute__((ext_vector_type(8))) short short8;
typedef __attribute__((ext_vector_type(4))) float f32x4;

// ---------------------------------------------------------------------------
// one grid-stride cast kernel: content -> c_bf; [k_w;v_w;b_w;ts_w] -> w_bf
// ---------------------------------------------------------------------------
__global__ __launch_bounds__(256) void cast_all(
    const float* __restrict__ content, const float* __restrict__ k_w,
    const float* __restrict__ v_w, const float* __restrict__ b_w,
    const float* __restrict__ ts_w, __hip_bfloat16* __restrict__ c_bf,
    __hip_bfloat16* __restrict__ w_bf) {
  const int total = NC8 + 2 * NW8 + 2 * NB8;
  int i = blockIdx.x * blockDim.x + threadIdx.x;
  const int stride = gridDim.x * blockDim.x;
  for (; i < total; i += stride) {
    const float* src;
    __hip_bfloat16* dst;
    int idx;
    if (i < NC8) { src = content; dst = c_bf; idx = i; }
    else if (i < NC8 + NW8) { src = k_w; dst = w_bf; idx = i - NC8; }
    else if (i < NC8 + 2 * NW8) {
      src = v_w; dst = w_bf + (size_t)1024 * D; idx = i - NC8 - NW8;
    } else if (i < NC8 + 2 * NW8 + NB8) {
      src = b_w; dst = w_bf + (size_t)2048 * D; idx = i - NC8 - 2 * NW8;
    } else {
      src = ts_w; dst = w_bf + (size_t)2064 * D; idx = i - NC8 - 2 * NW8 - NB8;
    }
    const float4 x = ((const float4*)src)[2 * idx];
    const float4 y = ((const float4*)src)[2 * idx + 1];
    __hip_bfloat16 tmp[8];
    tmp[0] = __float2bfloat16(x.x); tmp[1] = __float2bfloat16(x.y);
    tmp[2] = __float2bfloat16(x.z); tmp[3] = __float2bfloat16(x.w);
    tmp[4] = __float2bfloat16(y.x); tmp[5] = __float2bfloat16(y.y);
    tmp[6] = __float2bfloat16(y.z); tmp[7] = __float2bfloat16(y.w);
    *(uint4*)(dst + 8 * (size_t)idx) = *(const uint4*)tmp;
  }
}

// ---------------------------------------------------------------------------
// bf16 MFMA GEMM. 1-D grid of 1088 blocks; XCD (bid&7) owns a contiguous
// band of 8 m-tiles (4 MB of A, L2-resident) for all 17 n-tiles; nt changes
// every 8 consecutive blocks -> W temporally local. A fetched from HBM once.
// n-tile 16 = beta/gamma logits with fused sigmoid epilogue.
// ---------------------------------------------------------------------------
__global__ __launch_bounds__(256) void gemm_bf16(
    const __hip_bfloat16* __restrict__ A, const __hip_bfloat16* __restrict__ Wc,
    float* __restrict__ outk, const float* __restrict__ b_b,
    const float* __restrict__ ts_b, const float* __restrict__ hd,
    float* __restrict__ beta_out, float* __restrict__ gamma_out) {
  __shared__ __hip_bfloat16 As[128 * 32];
  __shared__ __hip_bfloat16 Bs[128 * 32];
  const int tid = threadIdx.x;
  const int bid = blockIdx.x;
  const int g = bid & 7, local = bid >> 3;
  const int nt = local >> 3, mt = g * 8 + (local & 7);
  const int m0 = mt * 128, n0 = nt * 128;
  const int w = tid >> 6, lane = tid & 63;
  const int wm = w & 1, wn = w >> 1;
  const int fr = lane & 15, fq = lane >> 4;
  const int srow = w * 16 + (lane >> 2);
  const int skc = (lane & 3) * 8;
  f32x4 acc[4][4] = {};
  for (int k0 = 0; k0 < D; k0 += 32) {
#pragma unroll
    for (int p = 0; p < 2; ++p) {
      const int row = p * 64 + srow;
      const int lo = p * 4096 + w * 1024;
      __builtin_amdgcn_global_load_lds(
          (const __attribute__((address_space(1))) void*)(A + (size_t)(m0 + row) * D + k0 + skc),
          (__attribute__((address_space(3))) void*)((char*)As + lo), 16, 0, 0);
      __builtin_amdgcn_global_load_lds(
          (const __attribute__((address_space(1))) void*)(Wc + (size_t)(n0 + row) * D + k0 + skc),
          (__attribute__((address_space(3))) void*)((char*)Bs + lo), 16, 0, 0);
    }
    __syncthreads();
    short8 af[4], bf[4];
#pragma unroll
    for (int i = 0; i < 4; ++i) {
      af[i] = *(const short8*)(As + (wm * 64 + i * 16 + fr) * 32 + fq * 8);
      bf[i] = *(const short8*)(Bs + (wn * 64 + i * 16 + fr) * 32 + fq * 8);
    }
#pragma unroll
    for (int i = 0; i < 4; ++i)
#pragma unroll
      for (int j = 0; j < 4; ++j)
        acc[i][j] = __builtin_amdgcn_mfma_f32_16x16x32_bf16(af[i], bf[j], acc[i][j], 0, 0, 0);
    __syncthreads();
  }
  if (n0 < 2048) {  // k/v projection tiles
#pragma unroll
    for (int i = 0; i < 4; ++i) {
      const int mbase = m0 + wm * 64 + i * 16 + fq * 4;
#pragma unroll
      for (int j = 0; j < 4; ++j) {
        const int n = n0 + wn * 64 + j * 16 + fr;
        const int h = (n >> 6) & 15, dk = n & 63;
        float* dst = outk + (size_t)(n >> 10) * BHTD;
#pragma unroll
        for (int r = 0; r < 4; ++r) {
          const int mm = mbase + r;
          const int b = mm >> 8, t = mm & 255;
          dst[(((size_t)b * H + h) * T + t) * DK + dk] = acc[i][j][r];
        }
      }
    }
  } else if (wn == 0) {  // beta/gamma tile: cols 0..15 beta, 16..31 gamma
    const int h = fr;
    const float bias_b = b_b[h];
    const float bias_g = ts_b[h] + hd[h];
#pragma unroll
    for (int i = 0; i < 4; ++i) {
      const int mbase = m0 + wm * 64 + i * 16 + fq * 4;
#pragma unroll
      for (int r = 0; r < 4; ++r) {
        const int mm = mbase + r;
        const int b = mm >> 8, t = mm & 255;
        const size_t oo = ((size_t)b * H + h) * T + t;
        beta_out[oo] = 1.f / (1.f + __expf(-(acc[i][0][r] + bias_b)));
        gamma_out[oo] = 1.f / (1.f + __expf(-(acc[i][1][r] + bias_g)));
      }
    }
  }
}

// ---------------------------------------------------------------------------
// Chunked solve (unchanged): per-chunk K staging, 2 blocks/CU.
// ---------------------------------------------------------------------------
__device__ __forceinline__ int cgi(int r, int g) {  // float4 index, chunk-local
  return r * 16 + (g & 8) + ((g ^ (r >> 2)) & 7);
}
__device__ __forceinline__ float rdlane(float x, int j) {
  return __int_as_float(__builtin_amdgcn_readlane(__float_as_int(x), j));
}

__global__ __launch_bounds__(256, 2) void solve_write(
    const float* __restrict__ kg, const float* __restrict__ vg,
    const float* __restrict__ betag, const float* __restrict__ gammag,
    const float* __restrict__ Wold, float* __restrict__ Wnew) {
  __shared__ float kC[64 * 64];
  __shared__ float Mm[64][68];
  __shared__ float Ss[64][68];
  __shared__ float Uu[64][68];
  __shared__ float s_beta[256], s_cl[256];
  float4* kC4 = (float4*)kC;

  const int tid = threadIdx.x;
  const int bh = blockIdx.x;
  const size_t base = (size_t)bh * T * DK;
  const int lane = tid & 63, wv = tid >> 6;
  const int th = tid >> 4, tl = tid & 15;

  s_beta[tid] = betag[(size_t)bh * T + tid];
  s_cl[tid] = __logf(fmaxf(gammag[(size_t)bh * T + tid], 1e-8f));
  __syncthreads();
  if (tid == 0) {
    float run = 0.f;
    for (int t = 0; t < T; ++t) { run += s_cl[t]; s_cl[t] = run; }
  }
  {  // M init = Wold^T
    const float* Wo = Wold + (size_t)bh * DK * DK;
    const int d = tid & 63, v0 = (tid >> 6) * 16;
#pragma unroll
    for (int u = 0; u < 16; ++u) Mm[d][v0 + u] = Wo[(size_t)(v0 + u) * DK + d];
  }
  __syncthreads();

  for (int c = 0; c < 4; ++c) {
    const int c0 = c * 64;
    const float oc = (c == 0) ? 0.f : s_cl[c0 - 1];
    const float on = s_cl[c0 + 63];

    {  // stage chunk K, normalized; 4 lanes per row
      const int r = tid >> 2, p = tid & 3;
      const float4* kp = (const float4*)(kg + base + (size_t)(c0 + r) * DK + p * 16);
      float4 x0 = kp[0], x1 = kp[1], x2 = kp[2], x3 = kp[3];
      float nrm = x0.x * x0.x + x0.y * x0.y + x0.z * x0.z + x0.w * x0.w +
                  x1.x * x1.x + x1.y * x1.y + x1.z * x1.z + x1.w * x1.w +
                  x2.x * x2.x + x2.y * x2.y + x2.z * x2.z + x2.w * x2.w +
                  x3.x * x3.x + x3.y * x3.y + x3.z * x3.z + x3.w * x3.w;
      nrm += __shfl_xor(nrm, 1, 64);
      nrm += __shfl_xor(nrm, 2, 64);
      const float rn = 1.f / fmaxf(sqrtf(nrm), 1e-12f);
      kC4[cgi(r, 4 * p + 0)] = make_float4(x0.x * rn, x0.y * rn, x0.z * rn, x0.w * rn);
      kC4[cgi(r, 4 * p + 1)] = make_float4(x1.x * rn, x1.y * rn, x1.z * rn, x1.w * rn);
      kC4[cgi(r, 4 * p + 2)] = make_float4(x2.x * rn, x2.y * rn, x2.z * rn, x2.w * rn);
      kC4[cgi(r, 4 * p + 3)] = make_float4(x3.x * rn, x3.y * rn, x3.z * rn, x3.w * rn);
    }
    __syncthreads();

    {  // P1: S = K_c K_c^T
      float accS[4][4] = {};
      for (int g = 0; g < 16; ++g) {
        float av[4][4], bv[4][4];
#pragma unroll
        for (int r = 0; r < 4; ++r) *(float4*)av[r] = kC4[cgi(4 * th + r, g)];
#pragma unroll
        for (int r = 0; r < 4; ++r) *(float4*)bv[r] = kC4[cgi(4 * tl + r, g)];
#pragma unroll
        for (int i = 0; i < 4; ++i)
#pragma unroll
          for (int j = 0; j < 4; ++j)
#pragma unroll
            for (int d = 0; d < 4; ++d) accS[i][j] += av[i][d] * bv[j][d];
      }
#pragma unroll
      for (int r = 0; r < 4; ++r)
        *(float4*)&Ss[4 * th + r][4 * tl] =
            make_float4(accS[r][0], accS[r][1], accS[r][2], accS[r][3]);
    }
    {  // P2: U = V_chunk - e^{ci} K_c M
      float acc2[4][4] = {};
      for (int dg = 0; dg < 16; ++dg) {
        float kv[4][4], mv[4][4];
#pragma unroll
        for (int r = 0; r < 4; ++r) *(float4*)kv[r] = kC4[cgi(4 * th + r, dg)];
#pragma unroll
        for (int r = 0; r < 4; ++r) *(float4*)mv[r] = *(const float4*)&Mm[4 * dg + r][4 * tl];
#pragma unroll
        for (int i = 0; i < 4; ++i)
#pragma unroll
          for (int d = 0; d < 4; ++d)
#pragma unroll
            for (int u = 0; u < 4; ++u) acc2[i][u] += kv[i][d] * mv[d][u];
      }
#pragma unroll
      for (int r = 0; r < 4; ++r) {
        const int gi = c0 + 4 * th + r;
        const float ci = (gi == 0) ? 0.f : s_cl[gi - 1] - oc;
        const float eci = __expf(ci);
        float4 vv = *(const float4*)(vg + base + (size_t)gi * DK + 4 * tl);
        *(float4*)&Uu[4 * th + r][4 * tl] =
            make_float4(vv.x - eci * acc2[r][0], vv.y - eci * acc2[r][1],
                        vv.z - eci * acc2[r][2], vv.w - eci * acc2[r][3]);
      }
    }
    __syncthreads();
    {  // P3: intra-chunk solve; wave wv owns v-range [16wv,16wv+16)
      const int gi = c0 + lane;
      const int v0 = wv * 16;
      float rhs[16];
#pragma unroll
      for (int u = 0; u < 4; ++u)
        *(float4*)&rhs[4 * u] = *(const float4*)&Uu[lane][v0 + 4 * u];
      const float ci = (gi == 0) ? 0.f : s_cl[gi - 1] - oc;
      const float ecl = __expf(ci);
      const float wgt = s_beta[gi] * __expf(-(s_cl[gi] - oc));
      for (int j = 0; j < 63; ++j) {
        const float wj = rdlane(wgt, j);
        const float sv = Ss[j][lane];
        const float co = (lane > j) ? ecl * wj * sv : 0.f;
#pragma unroll
        for (int u = 0; u < 16; ++u) rhs[u] -= co * rdlane(rhs[u], j);
      }
      const float ul = wgt * __expf(on - oc);
#pragma unroll
      for (int u = 0; u < 4; ++u)
        *(float4*)&Uu[lane][v0 + 4 * u] =
            make_float4(ul * rhs[4 * u], ul * rhs[4 * u + 1],
                        ul * rhs[4 * u + 2], ul * rhs[4 * u + 3]);
    }
    __syncthreads();
    {  // P4: M = e^{on-oc} M + K_c^T U
      const float rc = __expf(on - oc);
      const int d0 = 4 * th;
      float macc[4][4];
#pragma unroll
      for (int r = 0; r < 4; ++r) {
        float4 m4 = *(const float4*)&Mm[d0 + r][4 * tl];
        macc[r][0] = rc * m4.x; macc[r][1] = rc * m4.y;
        macc[r][2] = rc * m4.z; macc[r][3] = rc * m4.w;
      }
      for (int j = 0; j < 64; ++j) {
        float kj[4], uj[4];
        *(float4*)kj = kC4[cgi(j, th)];
        *(float4*)uj = *(const float4*)&Uu[j][4 * tl];
#pragma unroll
        for (int d = 0; d < 4; ++d)
#pragma unroll
          for (int u = 0; u < 4; ++u) macc[d][u] += kj[d] * uj[u];
      }
#pragma unroll
      for (int r = 0; r < 4; ++r)
        *(float4*)&Mm[d0 + r][4 * tl] =
            make_float4(macc[r][0], macc[r][1], macc[r][2], macc[r][3]);
    }
    __syncthreads();
  }
  {  // epilogue: W_new[v][d] = M[d][v]
    const int v = tid >> 2, d0 = (tid & 3) * 16;
    float* op = Wnew + (size_t)bh * DK * DK + (size_t)v * DK + d0;
#pragma unroll
    for (int u = 0; u < 4; ++u)
      *(float4*)(op + 4 * u) =
          make_float4(Mm[d0 + 4 * u + 0][v], Mm[d0 + 4 * u + 1][v],
                      Mm[d0 + 4 * u + 2][v], Mm[d0 + 4 * u + 3][v]);
  }
}

// ---------------------------------------------------------------------------
extern "C" void kernel_launch(void* const* d_in, const int* in_sizes, int n_in,
                              void* d_out, int out_size, void* d_ws, size_t ws_size,
                              hipStream_t stream) {
  const float* W_old = (const float*)d_in[0];
  const float* content = (const float*)d_in[1];
  const float* k_w = (const float*)d_in[2];
  const float* v_w = (const float*)d_in[3];
  const float* b_w = (const float*)d_in[4];
  const float* b_b = (const float*)d_in[5];
  const float* ts_w = (const float*)d_in[6];
  const float* ts_b = (const float*)d_in[7];
  const float* hd = (const float*)d_in[8];
  float* out = (float*)d_out;

  float* ws_k = (float*)d_ws;
  float* ws_v = ws_k + BHTD;
  float* ws_beta = ws_v + BHTD;
  float* ws_gamma = ws_beta + (size_t)B * H * T;
  __hip_bfloat16* c_bf = (__hip_bfloat16*)(ws_gamma + (size_t)B * H * T);
  __hip_bfloat16* w_bf = c_bf + (size_t)B * T * D;  // 2176 x 2048 region

  cast_all<<<2048, 256, 0, stream>>>(content, k_w, v_w, b_w, ts_w, c_bf, w_bf);
  gemm_bf16<<<dim3(1088), 256, 0, stream>>>(c_bf, w_bf, ws_k, b_b, ts_b, hd,
                                            ws_beta, ws_gamma);
  solve_write<<<dim3(B * H), 256, 0, stream>>>(ws_k, ws_v, ws_beta, ws_gamma,
                                               W_old, out);
}